// Round 5
// baseline (456.657 us; speedup 1.0000x reference)
//
#include <hip/hip_runtime.h>
#include <hip/hip_bf16.h>

#define DMODEL 1024
#define DI     2048
#define DSTATE 128
#define NH     32
#define HD     64
#define CONVD  2304
#define LSEQ   2048
#define BATCH  2
#define DPROJ  4384
#define DPROJ_PAD 4480
#define EPSV   1e-5f
#define QCH    128
#define NCH    16
#define TB     8

typedef __attribute__((ext_vector_type(8))) short bf16x8;
typedef __attribute__((ext_vector_type(4))) float f32x4;

// ---------------- conversion kernels ----------------

__global__ void f32_to_bf16_kernel(const float* __restrict__ in,
                                   __hip_bfloat16* __restrict__ out, int n4) {
  int i = blockIdx.x * 256 + threadIdx.x;
  if (i >= n4) return;
  float4 v = reinterpret_cast<const float4*>(in)[i];
  union { ushort4 u; __hip_bfloat16 h[4]; } cv;
  cv.h[0] = __float2bfloat16(v.x);
  cv.h[1] = __float2bfloat16(v.y);
  cv.h[2] = __float2bfloat16(v.z);
  cv.h[3] = __float2bfloat16(v.w);
  reinterpret_cast<ushort4*>(out)[i] = cv.u;
}

// out[n][k] = in[k][n] as bf16; zero-fill for n in [C, Cpad)
__global__ void transpose_f32_bf16(const float* __restrict__ in,
                                   __hip_bfloat16* __restrict__ out,
                                   int R, int C, int Cpad) {
  __shared__ float tile[32][33];
  int n0 = blockIdx.x * 32, k0 = blockIdx.y * 32;
  int tx = threadIdx.x, ty = threadIdx.y;  // (32,8)
#pragma unroll
  for (int j = 0; j < 32; j += 8) {
    int k = k0 + ty + j, n = n0 + tx;
    tile[ty + j][tx] = (n < C) ? in[(size_t)k * C + n] : 0.f;
  }
  __syncthreads();
#pragma unroll
  for (int j = 0; j < 32; j += 8) {
    int n = n0 + ty + j, k = k0 + tx;
    if (n < Cpad) out[(size_t)n * R + k] = __float2bfloat16(tile[tx][ty + j]);
  }
}

// ---------------- GEMM: C(MxN,f32) = A(MxK,bf16) * Bt(NxK,bf16)^T ----------------

__global__ __launch_bounds__(256, 2)
void gemm_bt_kernel(const __hip_bfloat16* __restrict__ A,
                    const __hip_bfloat16* __restrict__ Bt,
                    float* __restrict__ C,
                    int M, int N, int K, int NT) {
  __shared__ __hip_bfloat16 smA[128 * 32];
  __shared__ __hip_bfloat16 smB[128 * 32];
  const int bid = blockIdx.x;
  const int bm = (bid / NT) * 128;
  const int bn = (bid % NT) * 128;
  const int t = threadIdx.x;
  const int w = t >> 6, lane = t & 63;
  const int wr = (w >> 1) * 64, wc = (w & 1) * 64;

  f32x4 acc[4][4];
#pragma unroll
  for (int m = 0; m < 4; ++m)
#pragma unroll
    for (int n = 0; n < 4; ++n) acc[m][n] = (f32x4){0.f, 0.f, 0.f, 0.f};

  const int rl = lane >> 2;
  const int kof = (lane & 3) * 8;
  const size_t aBase0 = (size_t)(bm + w * 16 + rl) * K + kof;
  const size_t aBase1 = aBase0 + (size_t)64 * K;
  const size_t bBase0 = (size_t)(bn + w * 16 + rl) * K + kof;
  const size_t bBase1 = bBase0 + (size_t)64 * K;
  __hip_bfloat16* ldsA0 = smA + w * 512;
  __hip_bfloat16* ldsA1 = smA + w * 512 + 64 * 32;
  __hip_bfloat16* ldsB0 = smB + w * 512;
  __hip_bfloat16* ldsB1 = smB + w * 512 + 64 * 32;

  const int fr = lane & 15;
  const int fk = (lane >> 4) * 8;

  for (int k0 = 0; k0 < K; k0 += 32) {
    __builtin_amdgcn_global_load_lds((const __attribute__((address_space(1))) void*)(A + aBase0 + k0),
                                     (__attribute__((address_space(3))) void*)ldsA0, 16, 0, 0);
    __builtin_amdgcn_global_load_lds((const __attribute__((address_space(1))) void*)(A + aBase1 + k0),
                                     (__attribute__((address_space(3))) void*)ldsA1, 16, 0, 0);
    __builtin_amdgcn_global_load_lds((const __attribute__((address_space(1))) void*)(Bt + bBase0 + k0),
                                     (__attribute__((address_space(3))) void*)ldsB0, 16, 0, 0);
    __builtin_amdgcn_global_load_lds((const __attribute__((address_space(1))) void*)(Bt + bBase1 + k0),
                                     (__attribute__((address_space(3))) void*)ldsB1, 16, 0, 0);
    __syncthreads();
    bf16x8 af[4], bfv[4];
#pragma unroll
    for (int m = 0; m < 4; ++m)
      af[m] = *reinterpret_cast<const bf16x8*>(smA + (wr + m * 16 + fr) * 32 + fk);
#pragma unroll
    for (int n = 0; n < 4; ++n)
      bfv[n] = *reinterpret_cast<const bf16x8*>(smB + (wc + n * 16 + fr) * 32 + fk);
#pragma unroll
    for (int m = 0; m < 4; ++m)
#pragma unroll
      for (int n = 0; n < 4; ++n)
        acc[m][n] = __builtin_amdgcn_mfma_f32_16x16x32_bf16(af[m], bfv[n], acc[m][n], 0, 0, 0);
    __syncthreads();
  }

  const int r4 = (lane >> 4) * 4;
  const int cn = lane & 15;
#pragma unroll
  for (int m = 0; m < 4; ++m)
#pragma unroll
    for (int n = 0; n < 4; ++n) {
      int row = bm + wr + m * 16 + r4;
      int col = bn + wc + n * 16 + cn;
      float* cp = C + (size_t)row * N + col;
#pragma unroll
      for (int j = 0; j < 4; ++j) cp[(size_t)j * N] = acc[m][n][j];
    }
}

// ---------------- dt / decay precompute ----------------

__global__ void dtdecay_kernel(const float* __restrict__ zx, const float* __restrict__ dt_bias,
                               const float* __restrict__ A_log,
                               float* __restrict__ dtb, float* __restrict__ decb) {
  int idx = blockIdx.x * 256 + threadIdx.x;
  if (idx >= BATCH * LSEQ * NH) return;
  int h = idx & 31;
  int bl = idx >> 5;
  float v = zx[(size_t)bl * DPROJ_PAD + (DI + CONVD) + h] + dt_bias[h];
  float dt = (v > 20.f) ? v : log1pf(expf(v));
  float dec = expf(-expf(A_log[h]) * dt);
  dtb[idx] = dt;
  decb[idx] = dec;
}

// ---------------- causal depthwise conv + silu ----------------

__global__ void conv_silu_kernel(const float* __restrict__ zx, const float* __restrict__ cw,
                                 const float* __restrict__ cb, float* __restrict__ xbc) {
  int idx = blockIdx.x * 256 + threadIdx.x;
  if (idx >= BATCH * LSEQ * CONVD) return;
  int c = idx % CONVD;
  int bl = idx / CONVD;
  int l = bl % LSEQ;
  int b = bl / LSEQ;
  const float* src = zx + (size_t)b * LSEQ * DPROJ_PAD + DI + c;
  float acc = cb[c];
  float4 wv = *reinterpret_cast<const float4*>(cw + c * 4);
  if (l >= 3) acc += wv.x * src[(size_t)(l - 3) * DPROJ_PAD];
  if (l >= 2) acc += wv.y * src[(size_t)(l - 2) * DPROJ_PAD];
  if (l >= 1) acc += wv.z * src[(size_t)(l - 1) * DPROJ_PAD];
  acc += wv.w * src[(size_t)l * DPROJ_PAD];
  xbc[idx] = acc / (1.f + expf(-acc));
}

// ---------------- chunked scan, pass 1: local scans ----------------
// wg = (b,h,c). Thread partition (4p x 8n): lane = pg*16+ng; wave w covers
// p in [w*16,(w+1)*16); thread owns p = w*16+pg*4+[0,4) and n in
// {ng*4+[0,4)} u {64+ng*4+[0,4)}. LDS reads per step: 5 ds_read_b128
// (vs 16 in the 1p x 32n layout) -> off the LDS-throughput wall.

__global__ __launch_bounds__(256)
void ssd_local_kernel(const float* __restrict__ xbc, const float* __restrict__ dtb,
                      const float* __restrict__ decb, const float* __restrict__ Dparm,
                      float* __restrict__ y, __hip_bfloat16* __restrict__ sbuf,
                      float* __restrict__ pbuf) {
  __shared__ __align__(16) float bc[TB * 256];
  __shared__ __align__(16) float xb[TB * 64];
  __shared__ float dd[2 * TB];
  int bid = blockIdx.x;
  int c = bid & (NCH - 1);
  int h = (bid >> 4) & 31;
  int b = bid >> 9;
  int tid = threadIdx.x;
  int w = tid >> 6, l = tid & 63;
  int pg = l >> 4, ng = l & 15;
  int p0 = w * 16 + pg * 4;
  int t0 = c * QCH;

  const float* xc = xbc + (size_t)b * LSEQ * CONVD;
  float Dh = Dparm[h];

  f32x4 hA[4], hB[4];
#pragma unroll
  for (int pp = 0; pp < 4; ++pp) {
    hA[pp] = (f32x4){0.f, 0.f, 0.f, 0.f};
    hB[pp] = (f32x4){0.f, 0.f, 0.f, 0.f};
  }

  float pc = 1.f;
  for (int bb = 0; bb < QCH / TB; ++bb) {
    int tb0 = t0 + bb * TB;
    // ---- stage batch: B/C rows (256 f32 each), X rows (64 f32), dec/dt ----
    {
      const float* s0 = xc + (size_t)(tb0 + w) * CONVD + DI + l * 4;
      __builtin_amdgcn_global_load_lds((const __attribute__((address_space(1))) void*)s0,
                                       (__attribute__((address_space(3))) void*)(bc + w * 256), 16, 0, 0);
      const float* s1 = xc + (size_t)(tb0 + 4 + w) * CONVD + DI + l * 4;
      __builtin_amdgcn_global_load_lds((const __attribute__((address_space(1))) void*)s1,
                                       (__attribute__((address_space(3))) void*)(bc + 1024 + w * 256), 16, 0, 0);
    }
    if (w < 2) {
      const float* sx = xc + (size_t)(tb0 + w * 4 + (l >> 4)) * CONVD + h * HD + (l & 15) * 4;
      __builtin_amdgcn_global_load_lds((const __attribute__((address_space(1))) void*)sx,
                                       (__attribute__((address_space(3))) void*)(xb + w * 256), 16, 0, 0);
    }
    if (tid < 2 * TB) {
      int tt = tid & (TB - 1);
      const float* src = (tid < TB) ? decb : dtb;
      dd[tid] = src[((size_t)b * LSEQ + tb0 + tt) * NH + h];
    }
    __syncthreads();
    // ---- compute TB steps ----
#pragma unroll
    for (int tt = 0; tt < TB; ++tt) {
      float dec = dd[tt];
      float dts = dd[TB + tt];
      f32x4 xv = *reinterpret_cast<const f32x4*>(&xb[tt * 64 + p0]);
      f32x4 B0 = *reinterpret_cast<const f32x4*>(&bc[tt * 256 + ng * 4]);
      f32x4 B1 = *reinterpret_cast<const f32x4*>(&bc[tt * 256 + 64 + ng * 4]);
      f32x4 C0 = *reinterpret_cast<const f32x4*>(&bc[tt * 256 + 128 + ng * 4]);
      f32x4 C1 = *reinterpret_cast<const f32x4*>(&bc[tt * 256 + 192 + ng * 4]);
      f32x4 dv = {dec, dec, dec, dec};
      float ys[4];
#pragma unroll
      for (int pp = 0; pp < 4; ++pp) {
        float s = dts * xv[pp];
        f32x4 sv = {s, s, s, s};
        hA[pp] = hA[pp] * dv + sv * B0;
        hB[pp] = hB[pp] * dv + sv * B1;
        f32x4 a = hA[pp] * C0 + hB[pp] * C1;
        ys[pp] = (a[0] + a[1]) + (a[2] + a[3]);
      }
#pragma unroll
      for (int pp = 0; pp < 4; ++pp) {
        ys[pp] += __shfl_xor(ys[pp], 1);
        ys[pp] += __shfl_xor(ys[pp], 2);
        ys[pp] += __shfl_xor(ys[pp], 4);
        ys[pp] += __shfl_xor(ys[pp], 8);
      }
      pc *= dec;
      if (ng == 0) {
        float4 o;
        o.x = ys[0] + Dh * xv[0];
        o.y = ys[1] + Dh * xv[1];
        o.z = ys[2] + Dh * xv[2];
        o.w = ys[3] + Dh * xv[3];
        *reinterpret_cast<float4*>(&y[((size_t)b * LSEQ + tb0 + tt) * DI + h * HD + p0]) = o;
      }
    }
    __syncthreads();
  }
  // store local end-state: layout sbuf[bid][n][p]; pack 4 consecutive p per store
  __hip_bfloat16* sp = sbuf + (size_t)bid * 8192;
#pragma unroll
  for (int e = 0; e < 4; ++e) {
    union { ushort4 u; __hip_bfloat16 hh[4]; } pk;
    pk.hh[0] = __float2bfloat16(hA[0][e]);
    pk.hh[1] = __float2bfloat16(hA[1][e]);
    pk.hh[2] = __float2bfloat16(hA[2][e]);
    pk.hh[3] = __float2bfloat16(hA[3][e]);
    *reinterpret_cast<ushort4*>(sp + (ng * 4 + e) * 64 + p0) = pk.u;
    pk.hh[0] = __float2bfloat16(hB[0][e]);
    pk.hh[1] = __float2bfloat16(hB[1][e]);
    pk.hh[2] = __float2bfloat16(hB[2][e]);
    pk.hh[3] = __float2bfloat16(hB[3][e]);
    *reinterpret_cast<ushort4*>(sp + (64 + ng * 4 + e) * 64 + p0) = pk.u;
  }
  if (tid == 0) pbuf[bid] = pc;
}

// ---------------- chunked scan, pass 2: propagate chunk states ----------------

__global__ void ssd_prop_kernel(__hip_bfloat16* __restrict__ sbuf,
                                const float* __restrict__ pbuf) {
  int idx = blockIdx.x * 256 + threadIdx.x;   // 64 * 8192
  int bh = idx >> 13;
  int e = idx & 8191;
  __hip_bfloat16* base = sbuf + (size_t)bh * NCH * 8192 + e;
  const float* pb = pbuf + bh * NCH;
  float hs = 0.f;
  for (int cc = 0; cc < NCH; ++cc) {
    float sc = __bfloat162float(base[(size_t)cc * 8192]);
    base[(size_t)cc * 8192] = __float2bfloat16(hs);
    hs = fmaf(hs, pb[cc], sc);
  }
}

// ---------------- chunked scan, pass 3: cross-chunk correction ----------------

__global__ __launch_bounds__(256)
void ssd_corr_kernel(const float* __restrict__ xbc, const float* __restrict__ decb,
                     const __hip_bfloat16* __restrict__ sbuf, float* __restrict__ y) {
  int bid = blockIdx.x;
  int c = bid & (NCH - 1);
  if (c == 0) return;  // h_start = 0, no correction (block-uniform exit)
  __shared__ __align__(16) float cs[TB * 128];
  __shared__ float ddc[TB];
  int h = (bid >> 4) & 31;
  int b = bid >> 9;
  int tid = threadIdx.x;
  int w = tid >> 6, l = tid & 63;
  int pg = l >> 4, ng = l & 15;
  int p0 = w * 16 + pg * 4;
  int t0 = c * QCH;

  const float* xc = xbc + (size_t)b * LSEQ * CONVD;
  const __hip_bfloat16* sp = sbuf + (size_t)bid * 8192;
  f32x4 hA[4], hB[4];   // [pp] over e (n = ng*4+e / 64+ng*4+e)
#pragma unroll
  for (int e = 0; e < 4; ++e) {
    union { ushort4 u; __hip_bfloat16 hh[4]; } pk;
    pk.u = *reinterpret_cast<const ushort4*>(sp + (ng * 4 + e) * 64 + p0);
#pragma unroll
    for (int pp = 0; pp < 4; ++pp) hA[pp][e] = __bfloat162float(pk.hh[pp]);
    pk.u = *reinterpret_cast<const ushort4*>(sp + (64 + ng * 4 + e) * 64 + p0);
#pragma unroll
    for (int pp = 0; pp < 4; ++pp) hB[pp][e] = __bfloat162float(pk.hh[pp]);
  }

  float cum = 1.f;
  for (int bb = 0; bb < QCH / TB; ++bb) {
    int tb0 = t0 + bb * TB;
    {
      const float* sc = xc + (size_t)(tb0 + w * 2 + (l >> 5)) * CONVD + DI + DSTATE + (l & 31) * 4;
      __builtin_amdgcn_global_load_lds((const __attribute__((address_space(1))) void*)sc,
                                       (__attribute__((address_space(3))) void*)(cs + w * 256), 16, 0, 0);
    }
    if (tid < TB)
      ddc[tid] = decb[((size_t)b * LSEQ + tb0 + tid) * NH + h];
    __syncthreads();
#pragma unroll
    for (int tt = 0; tt < TB; ++tt) {
      float dec = ddc[tt];
      cum *= dec;
      f32x4 C0 = *reinterpret_cast<const f32x4*>(&cs[tt * 128 + ng * 4]);
      f32x4 C1 = *reinterpret_cast<const f32x4*>(&cs[tt * 128 + 64 + ng * 4]);
      float ys[4];
#pragma unroll
      for (int pp = 0; pp < 4; ++pp) {
        f32x4 a = hA[pp] * C0 + hB[pp] * C1;
        ys[pp] = (a[0] + a[1]) + (a[2] + a[3]);
      }
#pragma unroll
      for (int pp = 0; pp < 4; ++pp) {
        ys[pp] += __shfl_xor(ys[pp], 1);
        ys[pp] += __shfl_xor(ys[pp], 2);
        ys[pp] += __shfl_xor(ys[pp], 4);
        ys[pp] += __shfl_xor(ys[pp], 8);
      }
      if (ng == 0) {
        float* yp = &y[((size_t)b * LSEQ + tb0 + tt) * DI + h * HD + p0];
        float4 old = *reinterpret_cast<float4*>(yp);
        old.x += cum * ys[0];
        old.y += cum * ys[1];
        old.z += cum * ys[2];
        old.w += cum * ys[3];
        *reinterpret_cast<float4*>(yp) = old;
      }
    }
    __syncthreads();
  }
}

// ---------------- gating + RMS norm -> bf16 ----------------

__global__ __launch_bounds__(256)
void gate_rms_kernel(const float* __restrict__ y, const float* __restrict__ zx,
                     const float* __restrict__ nw, __hip_bfloat16* __restrict__ g) {
  int row = blockIdx.x;
  int t = threadIdx.x;
  const float* yr = y + (size_t)row * DI;
  const float* zr = zx + (size_t)row * DPROJ_PAD;
  float v[8];
  float ss = 0.f;
#pragma unroll
  for (int j = 0; j < 8; ++j) {
    int c = j * 256 + t;
    float z = zr[c];
    float vv = yr[c] * (z / (1.f + expf(-z)));
    v[j] = vv;
    ss += vv * vv;
  }
#pragma unroll
  for (int off = 32; off; off >>= 1) ss += __shfl_down(ss, off);
  __shared__ float red[4];
  if ((t & 63) == 0) red[t >> 6] = ss;
  __syncthreads();
  float tot = red[0] + red[1] + red[2] + red[3];
  float rstd = rsqrtf(tot * (1.f / DI) + EPSV);
#pragma unroll
  for (int j = 0; j < 8; ++j) {
    int c = j * 256 + t;
    g[(size_t)row * DI + c] = __float2bfloat16(v[j] * rstd * nw[c]);
  }
}

// ---------------- final RMS + residual ----------------

__global__ __launch_bounds__(256)
void final_rms_add(const float* __restrict__ o1, const float* __restrict__ x,
                   float* __restrict__ out) {
  int row = blockIdx.x;
  int t = threadIdx.x;
  const float* orow = o1 + (size_t)row * DMODEL;
  float v[4];
  float ss = 0.f;
#pragma unroll
  for (int j = 0; j < 4; ++j) {
    int c = j * 256 + t;
    float o = orow[c];
    v[j] = o;
    ss += o * o;
  }
#pragma unroll
  for (int off = 32; off; off >>= 1) ss += __shfl_down(ss, off);
  __shared__ float red[4];
  if ((t & 63) == 0) red[t >> 6] = ss;
  __syncthreads();
  float tot = red[0] + red[1] + red[2] + red[3];
  float rstd = rsqrtf(tot * (1.f / DMODEL) + EPSV);
#pragma unroll
  for (int j = 0; j < 4; ++j) {
    int c = j * 256 + t;
    out[(size_t)row * DMODEL + c] = v[j] * rstd + x[(size_t)row * DMODEL + c];
  }
}

// ---------------- launch ----------------

extern "C" void kernel_launch(void* const* d_in, const int* in_sizes, int n_in,
                              void* d_out, int out_size, void* d_ws, size_t ws_size,
                              hipStream_t stream) {
  const float* x       = (const float*)d_in[0];
  const float* W_in    = (const float*)d_in[1];
  const float* conv_w  = (const float*)d_in[2];
  const float* conv_b  = (const float*)d_in[3];
  const float* dt_bias = (const float*)d_in[4];
  const float* A_log   = (const float*)d_in[5];
  const float* Dp      = (const float*)d_in[6];
  const float* norm_w  = (const float*)d_in[7];
  const float* W_out   = (const float*)d_in[8];
  float* out = (float*)d_out;

  float* zx   = (float*)d_ws;                 // 4096 x 4480
  float* xbc  = zx + (size_t)18350080;        // 4096 x 2304
  float* ybuf = xbc + (size_t)9437184;        // 4096 x 2048
  float* dtb  = ybuf + (size_t)8388608;       // 131072
  float* decb = dtb + (size_t)131072;         // 131072
  __hip_bfloat16* xbf   = (__hip_bfloat16*)(decb + 131072);  // 4096x1024
  __hip_bfloat16* wtin  = xbf + (size_t)4194304;             // 4480x1024
  __hip_bfloat16* wtout = wtin + (size_t)4587520;            // 1024x2048
  float* pbuf = (float*)(wtout + (size_t)2097152);           // 1024 floats
  __hip_bfloat16* sbuf = xbf;  // overlay: xbf/wtin dead after GEMM1
  __hip_bfloat16* gbf = xbf;   // overlay: sbuf dead after ssd_corr
  float* o1 = xbc;             // overlay: xbc dead after ssd_corr

  f32_to_bf16_kernel<<<4096, 256, 0, stream>>>(x, xbf, 1048576);
  transpose_f32_bf16<<<dim3(140, 32), dim3(32, 8), 0, stream>>>(W_in, wtin, 1024, 4384, 4480);
  transpose_f32_bf16<<<dim3(32, 64), dim3(32, 8), 0, stream>>>(W_out, wtout, 2048, 1024, 1024);

  gemm_bt_kernel<<<1120, 256, 0, stream>>>(xbf, wtin, zx, 4096, 4480, 1024, 35);

  dtdecay_kernel<<<512, 256, 0, stream>>>(zx, dt_bias, A_log, dtb, decb);
  conv_silu_kernel<<<36864, 256, 0, stream>>>(zx, conv_w, conv_b, xbc);

  ssd_local_kernel<<<1024, 256, 0, stream>>>(xbc, dtb, decb, Dp, ybuf, sbuf, pbuf);
  ssd_prop_kernel<<<2048, 256, 0, stream>>>(sbuf, pbuf);
  ssd_corr_kernel<<<1024, 256, 0, stream>>>(xbc, decb, sbuf, ybuf);

  gate_rms_kernel<<<4096, 256, 0, stream>>>(ybuf, zx, norm_w, gbf);

  gemm_bt_kernel<<<256, 256, 0, stream>>>(gbf, wtout, o1, 4096, 1024, 2048, 8);

  final_rms_add<<<4096, 256, 0, stream>>>(o1, x, out);
}

// Round 6
// 268.556 us; speedup vs baseline: 1.7004x; 1.7004x over previous
//
#include <hip/hip_runtime.h>
#include <hip/hip_bf16.h>

#define DMODEL 1024
#define DI     2048
#define DSTATE 128
#define NH     32
#define HD     64
#define CONVD  2304
#define LSEQ   2048
#define BATCH  2
#define DPROJ  4384
#define DPROJ_PAD 4480
#define EPSV   1e-5f
#define QCH    128
#define NCH    16

typedef __attribute__((ext_vector_type(8))) short bf16x8;
typedef __attribute__((ext_vector_type(4))) float f32x4;

union U4 { ushort4 u; __hip_bfloat16 h[4]; };

// ---- swizzled LDS helpers for [rows][128] bf16 tiles (256B rows) ----
// byte ^= (row&7)<<4 : G4 fix for row-major-at-128 bank conflicts.
__device__ __forceinline__ bf16x8 ldsfrag(const __hip_bfloat16* base, int row, int ke) {
  int byte = row * 256 + ke * 2;
  byte ^= (row & 7) << 4;
  return *reinterpret_cast<const bf16x8*>(reinterpret_cast<const char*>(base) + byte);
}
__device__ __forceinline__ void ldswr4(__hip_bfloat16* base, int row, int col4, ushort4 v) {
  int byte = row * 256 + col4 * 2;
  byte ^= (row & 7) << 4;
  *reinterpret_cast<ushort4*>(reinterpret_cast<char*>(base) + byte) = v;
}
__device__ __forceinline__ ushort4 ldsrd4(const __hip_bfloat16* base, int row, int col4) {
  int byte = row * 256 + col4 * 2;
  byte ^= (row & 7) << 4;
  return *reinterpret_cast<const ushort4*>(reinterpret_cast<const char*>(base) + byte);
}
__device__ __forceinline__ void ldswr1(__hip_bfloat16* base, int row, int col, __hip_bfloat16 v) {
  int byte = row * 256 + col * 2;
  byte ^= (row & 7) << 4;
  *reinterpret_cast<__hip_bfloat16*>(reinterpret_cast<char*>(base) + byte) = v;
}
__device__ __forceinline__ ushort4 pack4(float x0, float x1, float x2, float x3) {
  U4 p;
  p.h[0] = __float2bfloat16(x0); p.h[1] = __float2bfloat16(x1);
  p.h[2] = __float2bfloat16(x2); p.h[3] = __float2bfloat16(x3);
  return p.u;
}

// ---------------- conversion kernels ----------------

__global__ void f32_to_bf16_kernel(const float* __restrict__ in,
                                   __hip_bfloat16* __restrict__ out, int n4) {
  int i = blockIdx.x * 256 + threadIdx.x;
  if (i >= n4) return;
  float4 v = reinterpret_cast<const float4*>(in)[i];
  reinterpret_cast<ushort4*>(out)[i] = pack4(v.x, v.y, v.z, v.w);
}

__global__ void transpose_f32_bf16(const float* __restrict__ in,
                                   __hip_bfloat16* __restrict__ out,
                                   int R, int C, int Cpad) {
  __shared__ float tile[32][33];
  int n0 = blockIdx.x * 32, k0 = blockIdx.y * 32;
  int tx = threadIdx.x, ty = threadIdx.y;  // (32,8)
#pragma unroll
  for (int j = 0; j < 32; j += 8) {
    int k = k0 + ty + j, n = n0 + tx;
    tile[ty + j][tx] = (n < C) ? in[(size_t)k * C + n] : 0.f;
  }
  __syncthreads();
#pragma unroll
  for (int j = 0; j < 32; j += 8) {
    int n = n0 + ty + j, k = k0 + tx;
    if (n < Cpad) out[(size_t)n * R + k] = __float2bfloat16(tile[tx][ty + j]);
  }
}

// ---------------- GEMM: C(MxN,f32) = A(MxK,bf16) * Bt(NxK,bf16)^T ----------------

__global__ __launch_bounds__(256, 2)
void gemm_bt_kernel(const __hip_bfloat16* __restrict__ A,
                    const __hip_bfloat16* __restrict__ Bt,
                    float* __restrict__ C,
                    int M, int N, int K, int NT) {
  __shared__ __hip_bfloat16 smA[128 * 32];
  __shared__ __hip_bfloat16 smB[128 * 32];
  const int bid = blockIdx.x;
  const int bm = (bid / NT) * 128;
  const int bn = (bid % NT) * 128;
  const int t = threadIdx.x;
  const int w = t >> 6, lane = t & 63;
  const int wr = (w >> 1) * 64, wc = (w & 1) * 64;

  f32x4 acc[4][4];
#pragma unroll
  for (int m = 0; m < 4; ++m)
#pragma unroll
    for (int n = 0; n < 4; ++n) acc[m][n] = (f32x4){0.f, 0.f, 0.f, 0.f};

  const int rl = lane >> 2;
  const int kof = (lane & 3) * 8;
  const size_t aBase0 = (size_t)(bm + w * 16 + rl) * K + kof;
  const size_t aBase1 = aBase0 + (size_t)64 * K;
  const size_t bBase0 = (size_t)(bn + w * 16 + rl) * K + kof;
  const size_t bBase1 = bBase0 + (size_t)64 * K;
  __hip_bfloat16* ldsA0 = smA + w * 512;
  __hip_bfloat16* ldsA1 = smA + w * 512 + 64 * 32;
  __hip_bfloat16* ldsB0 = smB + w * 512;
  __hip_bfloat16* ldsB1 = smB + w * 512 + 64 * 32;

  const int fr = lane & 15;
  const int fk = (lane >> 4) * 8;

  for (int k0 = 0; k0 < K; k0 += 32) {
    __builtin_amdgcn_global_load_lds((const __attribute__((address_space(1))) void*)(A + aBase0 + k0),
                                     (__attribute__((address_space(3))) void*)ldsA0, 16, 0, 0);
    __builtin_amdgcn_global_load_lds((const __attribute__((address_space(1))) void*)(A + aBase1 + k0),
                                     (__attribute__((address_space(3))) void*)ldsA1, 16, 0, 0);
    __builtin_amdgcn_global_load_lds((const __attribute__((address_space(1))) void*)(Bt + bBase0 + k0),
                                     (__attribute__((address_space(3))) void*)ldsB0, 16, 0, 0);
    __builtin_amdgcn_global_load_lds((const __attribute__((address_space(1))) void*)(Bt + bBase1 + k0),
                                     (__attribute__((address_space(3))) void*)ldsB1, 16, 0, 0);
    __syncthreads();
    bf16x8 af[4], bfv[4];
#pragma unroll
    for (int m = 0; m < 4; ++m)
      af[m] = *reinterpret_cast<const bf16x8*>(smA + (wr + m * 16 + fr) * 32 + fk);
#pragma unroll
    for (int n = 0; n < 4; ++n)
      bfv[n] = *reinterpret_cast<const bf16x8*>(smB + (wc + n * 16 + fr) * 32 + fk);
#pragma unroll
    for (int m = 0; m < 4; ++m)
#pragma unroll
      for (int n = 0; n < 4; ++n)
        acc[m][n] = __builtin_amdgcn_mfma_f32_16x16x32_bf16(af[m], bfv[n], acc[m][n], 0, 0, 0);
    __syncthreads();
  }

  const int r4 = (lane >> 4) * 4;
  const int cn = lane & 15;
#pragma unroll
  for (int m = 0; m < 4; ++m)
#pragma unroll
    for (int n = 0; n < 4; ++n) {
      int row = bm + wr + m * 16 + r4;
      int col = bn + wc + n * 16 + cn;
      float* cp = C + (size_t)row * N + col;
#pragma unroll
      for (int j = 0; j < 4; ++j) cp[(size_t)j * N] = acc[m][n][j];
    }
}

// ---------------- dt precompute ----------------

__global__ void dtdecay_kernel(const float* __restrict__ zx, const float* __restrict__ dt_bias,
                               float* __restrict__ dtb) {
  int idx = blockIdx.x * 256 + threadIdx.x;
  if (idx >= BATCH * LSEQ * NH) return;
  int h = idx & 31;
  int bl = idx >> 5;
  float v = zx[(size_t)bl * DPROJ_PAD + (DI + CONVD) + h] + dt_bias[h];
  float dt = (v > 20.f) ? v : log1pf(expf(v));
  dtb[idx] = dt;
}

// ---------------- causal depthwise conv + silu ----------------

__global__ void conv_silu_kernel(const float* __restrict__ zx, const float* __restrict__ cw,
                                 const float* __restrict__ cb, float* __restrict__ xbc) {
  int idx = blockIdx.x * 256 + threadIdx.x;
  if (idx >= BATCH * LSEQ * CONVD) return;
  int c = idx % CONVD;
  int bl = idx / CONVD;
  int l = bl % LSEQ;
  int b = bl / LSEQ;
  const float* src = zx + (size_t)b * LSEQ * DPROJ_PAD + DI + c;
  float acc = cb[c];
  float4 wv = *reinterpret_cast<const float4*>(cw + c * 4);
  if (l >= 3) acc += wv.x * src[(size_t)(l - 3) * DPROJ_PAD];
  if (l >= 2) acc += wv.y * src[(size_t)(l - 2) * DPROJ_PAD];
  if (l >= 1) acc += wv.z * src[(size_t)(l - 1) * DPROJ_PAD];
  acc += wv.w * src[(size_t)l * DPROJ_PAD];
  xbc[idx] = acc / (1.f + expf(-acc));
}

// ---------------- SSD pass 1: per-chunk MFMA (G^T -> L -> P -> Y, S) ----------------
// wg = (b,h,c), 4 waves. All big LDS tiles are [rows][128] bf16, XOR-swizzled.

__global__ __launch_bounds__(256, 1)
void ssd_mfma_local(const float* __restrict__ xbc, const float* __restrict__ dtb,
                    const float* __restrict__ A_log, const float* __restrict__ Dparm,
                    float* __restrict__ y, __hip_bfloat16* __restrict__ sbuf,
                    float* __restrict__ pbuf, float* __restrict__ cumdecb) {
  __shared__ __hip_bfloat16 sB[128 * 128];   // B natural [t][n]
  __shared__ __hip_bfloat16 sC[128 * 128];   // C natural [t][n]; becomes P [t][s]
  __shared__ __hip_bfloat16 sBT[128 * 128];  // B'^T [n][t], scaled by w_t
  __shared__ __hip_bfloat16 sXT[64 * 128];   // X^T [p][t]
  __shared__ float scs[128], sdt[128], sw[128];

  const int bid = blockIdx.x;
  const int c = bid & (NCH - 1);
  const int h = (bid >> 4) & 31;
  const int b = bid >> 9;
  const int tid = threadIdx.x;
  const int w = tid >> 6, lane = tid & 63;
  const int t0 = c * QCH;
  const float* xc = xbc + (size_t)b * LSEQ * CONVD;
  const float a = expf(A_log[h]);
  const float Dh = Dparm[h];

  // ---- phase 0: cumsum of dt (wave 0), decay weights ----
  if (w == 0) {
    const float* dtp = dtb + ((size_t)b * LSEQ + t0) * NH + h;
    float v0 = dtp[lane * NH];
    float v1 = dtp[(64 + lane) * NH];
    float s0 = v0;
#pragma unroll
    for (int off = 1; off < 64; off <<= 1) {
      float tv = __shfl_up(s0, off);
      if (lane >= off) s0 += tv;
    }
    float T0 = __shfl(s0, 63);
    float s1 = v1;
#pragma unroll
    for (int off = 1; off < 64; off <<= 1) {
      float tv = __shfl_up(s1, off);
      if (lane >= off) s1 += tv;
    }
    float cs1 = s1 + T0;
    float Tt = __shfl(s1, 63) + T0;
    scs[lane] = s0;       scs[64 + lane] = cs1;
    sdt[lane] = v0;       sdt[64 + lane] = v1;
    sw[lane] = v0 * expf(-a * (Tt - s0));
    sw[64 + lane] = v1 * expf(-a * (Tt - cs1));
    cumdecb[bid * 128 + lane] = expf(-a * s0);
    cumdecb[bid * 128 + 64 + lane] = expf(-a * cs1);
    if (lane == 0) pbuf[bid] = expf(-a * Tt);
  }
  __syncthreads();

  // ---- phase 1: stage B, C, B'T, XT (bf16, swizzled) ----
#pragma unroll
  for (int r = 0; r < 16; ++r) {
    int t = r * 8 + (tid >> 5);
    int n0 = (tid & 31) * 4;
    const float* row = xc + (size_t)(t0 + t) * CONVD + DI;
    float4 Bv = *reinterpret_cast<const float4*>(row + n0);
    float4 Cv = *reinterpret_cast<const float4*>(row + DSTATE + n0);
    ldswr4(sB, t, n0, pack4(Bv.x, Bv.y, Bv.z, Bv.w));
    ldswr4(sC, t, n0, pack4(Cv.x, Cv.y, Cv.z, Cv.w));
    float wt = sw[t];
    ldswr1(sBT, n0 + 0, t, __float2bfloat16(Bv.x * wt));
    ldswr1(sBT, n0 + 1, t, __float2bfloat16(Bv.y * wt));
    ldswr1(sBT, n0 + 2, t, __float2bfloat16(Bv.z * wt));
    ldswr1(sBT, n0 + 3, t, __float2bfloat16(Bv.w * wt));
  }
#pragma unroll
  for (int r = 0; r < 8; ++r) {
    int t = r * 16 + (tid >> 4);
    int p0 = (tid & 15) * 4;
    float4 Xv = *reinterpret_cast<const float4*>(xc + (size_t)(t0 + t) * CONVD + h * HD + p0);
    ldswr1(sXT, p0 + 0, t, __float2bfloat16(Xv.x));
    ldswr1(sXT, p0 + 1, t, __float2bfloat16(Xv.y));
    ldswr1(sXT, p0 + 2, t, __float2bfloat16(Xv.z));
    ldswr1(sXT, p0 + 3, t, __float2bfloat16(Xv.w));
  }
  __syncthreads();

  const int fr = lane & 15;
  const int fk = (lane >> 4) * 8;
  const int rb = (lane >> 4) * 4;

  // ---- phase 2: G^T[s][t] = sum_n B[s][n] C[t][n]; wave quadrant 64x64 ----
  const int sR0 = (w >> 1) * 64, tC0 = (w & 1) * 64;
  f32x4 g[4][4];
#pragma unroll
  for (int m = 0; m < 4; ++m)
#pragma unroll
    for (int n = 0; n < 4; ++n) g[m][n] = (f32x4){0.f, 0.f, 0.f, 0.f};
  for (int kk = 0; kk < 128; kk += 32) {
    bf16x8 af[4], bfv[4];
#pragma unroll
    for (int m = 0; m < 4; ++m) af[m] = ldsfrag(sB, sR0 + m * 16 + fr, kk + fk);
#pragma unroll
    for (int n = 0; n < 4; ++n) bfv[n] = ldsfrag(sC, tC0 + n * 16 + fr, kk + fk);
#pragma unroll
    for (int m = 0; m < 4; ++m)
#pragma unroll
      for (int n = 0; n < 4; ++n)
        g[m][n] = __builtin_amdgcn_mfma_f32_16x16x32_bf16(af[m], bfv[n], g[m][n], 0, 0, 0);
  }
  __syncthreads();  // all waves done reading sB/sC

  // ---- apply causal decay mask L, write P[t][s] into sC's slot ----
#pragma unroll
  for (int m = 0; m < 4; ++m) {
    int sb0 = sR0 + m * 16 + rb;
    float cs_s[4], dt_s[4];
#pragma unroll
    for (int j = 0; j < 4; ++j) { cs_s[j] = scs[sb0 + j]; dt_s[j] = sdt[sb0 + j]; }
#pragma unroll
    for (int n = 0; n < 4; ++n) {
      int t = tC0 + n * 16 + fr;
      float cst = scs[t];
      float vv[4];
#pragma unroll
      for (int j = 0; j < 4; ++j) {
        int s = sb0 + j;
        float e = expf(-a * (cst - cs_s[j])) * dt_s[j];
        vv[j] = (s <= t) ? g[m][n][j] * e : 0.f;
      }
      ldswr4(sC, t, sb0, pack4(vv[0], vv[1], vv[2], vv[3]));
    }
  }
  __syncthreads();

  // ---- phase 3: Y[t][p] = sum_s P[t][s] X[s][p] (+ D*x, f32) ----
  {
    int tR0 = w * 32;
    f32x4 yac[2][4];
#pragma unroll
    for (int m = 0; m < 2; ++m)
#pragma unroll
      for (int n = 0; n < 4; ++n) yac[m][n] = (f32x4){0.f, 0.f, 0.f, 0.f};
    for (int kk = 0; kk < 128; kk += 32) {
      bf16x8 af[2], bfv[4];
#pragma unroll
      for (int m = 0; m < 2; ++m) af[m] = ldsfrag(sC, tR0 + m * 16 + fr, kk + fk);
#pragma unroll
      for (int n = 0; n < 4; ++n) bfv[n] = ldsfrag(sXT, n * 16 + fr, kk + fk);
#pragma unroll
      for (int m = 0; m < 2; ++m)
#pragma unroll
        for (int n = 0; n < 4; ++n)
          yac[m][n] = __builtin_amdgcn_mfma_f32_16x16x32_bf16(af[m], bfv[n], yac[m][n], 0, 0, 0);
    }
#pragma unroll
    for (int m = 0; m < 2; ++m)
#pragma unroll
      for (int n = 0; n < 4; ++n) {
        int trow = tR0 + m * 16 + rb;
        int pc = n * 16 + fr;
        float* yp = y + ((size_t)b * LSEQ + t0 + trow) * DI + h * HD + pc;
        const float* xp = xc + (size_t)(t0 + trow) * CONVD + h * HD + pc;
#pragma unroll
        for (int j = 0; j < 4; ++j)
          yp[(size_t)j * DI] = yac[m][n][j] + Dh * xp[(size_t)j * CONVD];
      }
  }

  // ---- phase 4: S^T[p][n] = sum_t XT[p][t] B'T[n][t] -> sbuf[bid][p][n] ----
  {
    int pR0 = (w >> 1) * 32, nC0 = (w & 1) * 64;
    f32x4 sac[2][4];
#pragma unroll
    for (int m = 0; m < 2; ++m)
#pragma unroll
      for (int n = 0; n < 4; ++n) sac[m][n] = (f32x4){0.f, 0.f, 0.f, 0.f};
    for (int kk = 0; kk < 128; kk += 32) {
      bf16x8 af[2], bfv[4];
#pragma unroll
      for (int m = 0; m < 2; ++m) af[m] = ldsfrag(sXT, pR0 + m * 16 + fr, kk + fk);
#pragma unroll
      for (int n = 0; n < 4; ++n) bfv[n] = ldsfrag(sBT, nC0 + n * 16 + fr, kk + fk);
#pragma unroll
      for (int m = 0; m < 2; ++m)
#pragma unroll
        for (int n = 0; n < 4; ++n)
          sac[m][n] = __builtin_amdgcn_mfma_f32_16x16x32_bf16(af[m], bfv[n], sac[m][n], 0, 0, 0);
    }
    __hip_bfloat16* sg = sbuf + (size_t)bid * 8192;
#pragma unroll
    for (int m = 0; m < 2; ++m)
#pragma unroll
      for (int n = 0; n < 4; ++n) {
        int p = pR0 + m * 16 + rb;
        int nn = nC0 + n * 16 + fr;
#pragma unroll
        for (int j = 0; j < 4; ++j)
          sg[(size_t)(p + j) * 128 + nn] = __float2bfloat16(sac[m][n][j]);
      }
  }
}

// ---------------- SSD pass 2: propagate chunk states (unchanged) ----------------

__global__ void ssd_prop_kernel(__hip_bfloat16* __restrict__ sbuf,
                                const float* __restrict__ pbuf) {
  int idx = blockIdx.x * 256 + threadIdx.x;   // 64 * 8192
  int bh = idx >> 13;
  int e = idx & 8191;
  __hip_bfloat16* base = sbuf + (size_t)bh * NCH * 8192 + e;
  const float* pb = pbuf + bh * NCH;
  float hs = 0.f;
  for (int cc = 0; cc < NCH; ++cc) {
    float sc = __bfloat162float(base[(size_t)cc * 8192]);
    base[(size_t)cc * 8192] = __float2bfloat16(hs);
    hs = fmaf(hs, pb[cc], sc);
  }
}

// ---------------- SSD pass 3: Y += diag(cumdec) * C @ h_start (MFMA) ----------------

__global__ __launch_bounds__(256)
void ssd_mfma_corr(const float* __restrict__ xbc, const __hip_bfloat16* __restrict__ sbuf,
                   const float* __restrict__ cumdecb, float* __restrict__ y) {
  __shared__ __hip_bfloat16 sC[128 * 128];
  __shared__ __hip_bfloat16 sH[64 * 128];
  __shared__ float scd[128];
  const int bid = blockIdx.x;
  const int c = bid & (NCH - 1);
  if (c == 0) return;  // block-uniform exit
  const int h = (bid >> 4) & 31;
  const int b = bid >> 9;
  const int tid = threadIdx.x;
  const int w = tid >> 6, lane = tid & 63;
  const int t0 = c * QCH;
  const float* xc = xbc + (size_t)b * LSEQ * CONVD;

#pragma unroll
  for (int r = 0; r < 16; ++r) {
    int t = r * 8 + (tid >> 5);
    int n0 = (tid & 31) * 4;
    float4 Cv = *reinterpret_cast<const float4*>(xc + (size_t)(t0 + t) * CONVD + DI + DSTATE + n0);
    ldswr4(sC, t, n0, pack4(Cv.x, Cv.y, Cv.z, Cv.w));
  }
#pragma unroll
  for (int r = 0; r < 8; ++r) {
    int p = r * 8 + (tid >> 5);
    int n0 = (tid & 31) * 4;
    ushort4 hv = *reinterpret_cast<const ushort4*>(sbuf + (size_t)bid * 8192 + p * 128 + n0);
    ldswr4(sH, p, n0, hv);
  }
  if (tid < 128) scd[tid] = cumdecb[bid * 128 + tid];
  __syncthreads();

  const int fr = lane & 15;
  const int fk = (lane >> 4) * 8;
  const int rb = (lane >> 4) * 4;
  int tR0 = w * 32;
  f32x4 ac[2][4];
#pragma unroll
  for (int m = 0; m < 2; ++m)
#pragma unroll
    for (int n = 0; n < 4; ++n) ac[m][n] = (f32x4){0.f, 0.f, 0.f, 0.f};
  for (int kk = 0; kk < 128; kk += 32) {
    bf16x8 af[2], bfv[4];
#pragma unroll
    for (int m = 0; m < 2; ++m) af[m] = ldsfrag(sC, tR0 + m * 16 + fr, kk + fk);
#pragma unroll
    for (int n = 0; n < 4; ++n) bfv[n] = ldsfrag(sH, n * 16 + fr, kk + fk);
#pragma unroll
    for (int m = 0; m < 2; ++m)
#pragma unroll
      for (int n = 0; n < 4; ++n)
        ac[m][n] = __builtin_amdgcn_mfma_f32_16x16x32_bf16(af[m], bfv[n], ac[m][n], 0, 0, 0);
  }
#pragma unroll
  for (int m = 0; m < 2; ++m)
#pragma unroll
    for (int n = 0; n < 4; ++n) {
      int trow = tR0 + m * 16 + rb;
      int pc = n * 16 + fr;
      float* yp = y + ((size_t)b * LSEQ + t0 + trow) * DI + h * HD + pc;
#pragma unroll
      for (int j = 0; j < 4; ++j)
        yp[(size_t)j * DI] += scd[trow + j] * ac[m][n][j];
    }
}

// ---------------- gating + RMS norm -> bf16 ----------------

__global__ __launch_bounds__(256)
void gate_rms_kernel(const float* __restrict__ y, const float* __restrict__ zx,
                     const float* __restrict__ nw, __hip_bfloat16* __restrict__ g) {
  int row = blockIdx.x;
  int t = threadIdx.x;
  const float* yr = y + (size_t)row * DI;
  const float* zr = zx + (size_t)row * DPROJ_PAD;
  float v[8];
  float ss = 0.f;
#pragma unroll
  for (int j = 0; j < 8; ++j) {
    int c = j * 256 + t;
    float z = zr[c];
    float vv = yr[c] * (z / (1.f + expf(-z)));
    v[j] = vv;
    ss += vv * vv;
  }
#pragma unroll
  for (int off = 32; off; off >>= 1) ss += __shfl_down(ss, off);
  __shared__ float red[4];
  if ((t & 63) == 0) red[t >> 6] = ss;
  __syncthreads();
  float tot = red[0] + red[1] + red[2] + red[3];
  float rstd = rsqrtf(tot * (1.f / DI) + EPSV);
#pragma unroll
  for (int j = 0; j < 8; ++j) {
    int c = j * 256 + t;
    g[(size_t)row * DI + c] = __float2bfloat16(v[j] * rstd * nw[c]);
  }
}

// ---------------- final RMS + residual ----------------

__global__ __launch_bounds__(256)
void final_rms_add(const float* __restrict__ o1, const float* __restrict__ x,
                   float* __restrict__ out) {
  int row = blockIdx.x;
  int t = threadIdx.x;
  const float* orow = o1 + (size_t)row * DMODEL;
  float v[4];
  float ss = 0.f;
#pragma unroll
  for (int j = 0; j < 4; ++j) {
    int c = j * 256 + t;
    float o = orow[c];
    v[j] = o;
    ss += o * o;
  }
#pragma unroll
  for (int off = 32; off; off >>= 1) ss += __shfl_down(ss, off);
  __shared__ float red[4];
  if ((t & 63) == 0) red[t >> 6] = ss;
  __syncthreads();
  float tot = red[0] + red[1] + red[2] + red[3];
  float rstd = rsqrtf(tot * (1.f / DMODEL) + EPSV);
#pragma unroll
  for (int j = 0; j < 4; ++j) {
    int c = j * 256 + t;
    out[(size_t)row * DMODEL + c] = v[j] * rstd + x[(size_t)row * DMODEL + c];
  }
}

// ---------------- launch ----------------

extern "C" void kernel_launch(void* const* d_in, const int* in_sizes, int n_in,
                              void* d_out, int out_size, void* d_ws, size_t ws_size,
                              hipStream_t stream) {
  const float* x       = (const float*)d_in[0];
  const float* W_in    = (const float*)d_in[1];
  const float* conv_w  = (const float*)d_in[2];
  const float* conv_b  = (const float*)d_in[3];
  const float* dt_bias = (const float*)d_in[4];
  const float* A_log   = (const float*)d_in[5];
  const float* Dp      = (const float*)d_in[6];
  const float* norm_w  = (const float*)d_in[7];
  const float* W_out   = (const float*)d_in[8];
  float* out = (float*)d_out;

  float* zx   = (float*)d_ws;                 // 4096 x 4480
  float* xbc  = zx + (size_t)18350080;        // 4096 x 2304
  float* ybuf = xbc + (size_t)9437184;        // 4096 x 2048
  float* dtb  = ybuf + (size_t)8388608;       // 131072
  float* cumdecb = dtb + (size_t)131072;      // 131072 (recycled decb slot: 1024 x 128)
  __hip_bfloat16* xbf   = (__hip_bfloat16*)(cumdecb + 131072); // 4096x1024
  __hip_bfloat16* wtin  = xbf + (size_t)4194304;               // 4480x1024
  __hip_bfloat16* wtout = wtin + (size_t)4587520;              // 1024x2048
  float* pbuf = (float*)(wtout + (size_t)2097152);             // 1024 floats
  __hip_bfloat16* sbuf = xbf;  // overlay: xbf/wtin dead after GEMM1 (8,388,608 bf16)
  __hip_bfloat16* gbf = xbf;   // overlay: sbuf dead after ssd_mfma_corr
  float* o1 = xbc;             // overlay: xbc dead after ssd_mfma_corr

  f32_to_bf16_kernel<<<4096, 256, 0, stream>>>(x, xbf, 1048576);
  transpose_f32_bf16<<<dim3(140, 32), dim3(32, 8), 0, stream>>>(W_in, wtin, 1024, 4384, 4480);
  transpose_f32_bf16<<<dim3(32, 64), dim3(32, 8), 0, stream>>>(W_out, wtout, 2048, 1024, 1024);

  gemm_bt_kernel<<<1120, 256, 0, stream>>>(xbf, wtin, zx, 4096, 4480, 1024, 35);

  dtdecay_kernel<<<512, 256, 0, stream>>>(zx, dt_bias, dtb);
  conv_silu_kernel<<<36864, 256, 0, stream>>>(zx, conv_w, conv_b, xbc);

  ssd_mfma_local<<<1024, 256, 0, stream>>>(xbc, dtb, A_log, Dp, ybuf, sbuf, pbuf, cumdecb);
  ssd_prop_kernel<<<2048, 256, 0, stream>>>(sbuf, pbuf);
  ssd_mfma_corr<<<1024, 256, 0, stream>>>(xbc, sbuf, cumdecb, ybuf);

  gate_rms_kernel<<<4096, 256, 0, stream>>>(ybuf, zx, norm_w, gbf);

  gemm_bt_kernel<<<256, 256, 0, stream>>>(gbf, wtout, o1, 4096, 1024, 2048, 8);

  final_rms_add<<<4096, 256, 0, stream>>>(o1, x, out);
}

// Round 7
// 251.304 us; speedup vs baseline: 1.8172x; 1.0687x over previous
//
#include <hip/hip_runtime.h>
#include <hip/hip_bf16.h>

#define DMODEL 1024
#define DI     2048
#define DSTATE 128
#define NH     32
#define HD     64
#define CONVD  2304
#define LSEQ   2048
#define BATCH  2
#define DPROJ  4384
#define DPROJ_PAD 4480
#define EPSV   1e-5f
#define QCH    128
#define NCH    16

#define AS1 __attribute__((address_space(1)))
#define AS3 __attribute__((address_space(3)))

typedef __attribute__((ext_vector_type(8))) short bf16x8;
typedef __attribute__((ext_vector_type(4))) float f32x4;

union U4 { ushort4 u; __hip_bfloat16 h[4]; };

__device__ __forceinline__ float bf2f(unsigned short u) {
  union { unsigned int i; float f; } c; c.i = ((unsigned)u) << 16; return c.f;
}
__device__ __forceinline__ unsigned short f2bf(float f) {
  __hip_bfloat16 h = __float2bfloat16(f);
  return *reinterpret_cast<unsigned short*>(&h);
}
__device__ __forceinline__ ushort4 pack4(float x0, float x1, float x2, float x3) {
  U4 p;
  p.h[0] = __float2bfloat16(x0); p.h[1] = __float2bfloat16(x1);
  p.h[2] = __float2bfloat16(x2); p.h[3] = __float2bfloat16(x3);
  return p.u;
}

// ---- swizzled LDS helpers: [rows][128] bf16 tiles (256B rows), byte ^= (row&7)<<4 ----
__device__ __forceinline__ bf16x8 ldsfrag(const __hip_bfloat16* base, int row, int ke) {
  int byte = row * 256 + ke * 2;
  byte ^= (row & 7) << 4;
  return *reinterpret_cast<const bf16x8*>(reinterpret_cast<const char*>(base) + byte);
}
__device__ __forceinline__ void ldswr4(__hip_bfloat16* base, int row, int col4, ushort4 v) {
  int byte = row * 256 + col4 * 2;
  byte ^= (row & 7) << 4;
  *reinterpret_cast<ushort4*>(reinterpret_cast<char*>(base) + byte) = v;
}
__device__ __forceinline__ void ldswr1u(__hip_bfloat16* base, int row, int col, unsigned short v) {
  int byte = row * 256 + col * 2;
  byte ^= (row & 7) << 4;
  *reinterpret_cast<unsigned short*>(reinterpret_cast<char*>(base) + byte) = v;
}
// ---- swizzled helpers for [rows][64] bf16 tiles (128B rows), same XOR ----
__device__ __forceinline__ bf16x8 frag64(const __hip_bfloat16* base, int row, int ke) {
  int byte = row * 128 + ke * 2;
  byte ^= (row & 7) << 4;
  return *reinterpret_cast<const bf16x8*>(reinterpret_cast<const char*>(base) + byte);
}

// ---------------- conversion kernels ----------------

__global__ void f32_to_bf16_kernel(const float* __restrict__ in,
                                   __hip_bfloat16* __restrict__ out, int n4) {
  int i = blockIdx.x * 256 + threadIdx.x;
  if (i >= n4) return;
  float4 v = reinterpret_cast<const float4*>(in)[i];
  reinterpret_cast<ushort4*>(out)[i] = pack4(v.x, v.y, v.z, v.w);
}

__global__ void transpose_f32_bf16(const float* __restrict__ in,
                                   __hip_bfloat16* __restrict__ out,
                                   int R, int C, int Cpad) {
  __shared__ float tile[32][33];
  int n0 = blockIdx.x * 32, k0 = blockIdx.y * 32;
  int tx = threadIdx.x, ty = threadIdx.y;  // (32,8)
#pragma unroll
  for (int j = 0; j < 32; j += 8) {
    int k = k0 + ty + j, n = n0 + tx;
    tile[ty + j][tx] = (n < C) ? in[(size_t)k * C + n] : 0.f;
  }
  __syncthreads();
#pragma unroll
  for (int j = 0; j < 32; j += 8) {
    int n = n0 + ty + j, k = k0 + tx;
    if (n < Cpad) out[(size_t)n * R + k] = __float2bfloat16(tile[tx][ty + j]);
  }
}

// ---------------- GEMM v2: 128x128 tile, BK=64, double-buffered 2-phase, T2 swizzle ----
// C(MxN,f32) = A(MxK,bf16) * Bt(NxK,bf16)^T.  nwg must be %8==0 (XCD swizzle).

__global__ __launch_bounds__(256, 2)
void gemm_bt2(const __hip_bfloat16* __restrict__ A,
              const __hip_bfloat16* __restrict__ Bt,
              float* __restrict__ C,
              int M, int N, int K, int NT, int CPX) {
  __shared__ __hip_bfloat16 smA[2][128 * 64];
  __shared__ __hip_bfloat16 smB[2][128 * 64];
  const int orig = blockIdx.x;
  const int wg = (orig & 7) * CPX + (orig >> 3);
  const int bm = (wg / NT) * 128;
  const int bn = (wg % NT) * 128;
  const int t = threadIdx.x;
  const int w = t >> 6, lane = t & 63;
  const int wr = (w >> 1) * 64, wc = (w & 1) * 64;
  const int fr = lane & 15, fk = (lane >> 4) * 8;
  // staging: per load, 8 rows x 8 chunks; lane -> (row=lane>>3, phys chunk=lane&7)
  // inverse-swizzled source chunk so that swizzled frag64 reads return natural data
  const int srow = lane >> 3;
  const int scol = ((lane & 7) ^ srow) * 8;

  f32x4 acc[4][4];
#pragma unroll
  for (int m = 0; m < 4; ++m)
#pragma unroll
    for (int n = 0; n < 4; ++n) acc[m][n] = (f32x4){0.f, 0.f, 0.f, 0.f};

  const __hip_bfloat16* aSrc = A + (size_t)(bm + srow) * K + scol;
  const __hip_bfloat16* bSrc = Bt + (size_t)(bn + srow) * K + scol;

  auto STAGE = [&](int buf, int k0) {
#pragma unroll
    for (int i = 0; i < 4; ++i) {
      int ro = w * 32 + i * 8;
      __builtin_amdgcn_global_load_lds((const AS1 void*)(aSrc + (size_t)ro * K + k0),
                                       (AS3 void*)(&smA[buf][ro * 64]), 16, 0, 0);
      __builtin_amdgcn_global_load_lds((const AS1 void*)(bSrc + (size_t)ro * K + k0),
                                       (AS3 void*)(&smB[buf][ro * 64]), 16, 0, 0);
    }
  };

  STAGE(0, 0);
  __syncthreads();
  const int nt = K >> 6;
  int cur = 0;
  for (int kt = 0; kt < nt; ++kt) {
    if (kt + 1 < nt) STAGE(cur ^ 1, (kt + 1) << 6);
#pragma unroll
    for (int kk = 0; kk < 64; kk += 32) {
      bf16x8 af[4], bfv[4];
#pragma unroll
      for (int m = 0; m < 4; ++m) af[m] = frag64(&smA[cur][0], wr + m * 16 + fr, kk + fk);
#pragma unroll
      for (int n = 0; n < 4; ++n) bfv[n] = frag64(&smB[cur][0], wc + n * 16 + fr, kk + fk);
#pragma unroll
      for (int m = 0; m < 4; ++m)
#pragma unroll
        for (int n = 0; n < 4; ++n)
          acc[m][n] = __builtin_amdgcn_mfma_f32_16x16x32_bf16(af[m], bfv[n], acc[m][n], 0, 0, 0);
    }
    __syncthreads();
    cur ^= 1;
  }

  const int r4 = (lane >> 4) * 4;
  const int cn = lane & 15;
#pragma unroll
  for (int m = 0; m < 4; ++m)
#pragma unroll
    for (int n = 0; n < 4; ++n) {
      int row = bm + wr + m * 16 + r4;
      int col = bn + wc + n * 16 + cn;
      float* cp = C + (size_t)row * N + col;
#pragma unroll
      for (int j = 0; j < 4; ++j) cp[(size_t)j * N] = acc[m][n][j];
    }
}

// ---------------- dt precompute ----------------

__global__ void dtdecay_kernel(const float* __restrict__ zx, const float* __restrict__ dt_bias,
                               float* __restrict__ dtb) {
  int idx = blockIdx.x * 256 + threadIdx.x;
  if (idx >= BATCH * LSEQ * NH) return;
  int h = idx & 31;
  int bl = idx >> 5;
  float v = zx[(size_t)bl * DPROJ_PAD + (DI + CONVD) + h] + dt_bias[h];
  float dt = (v > 20.f) ? v : log1pf(expf(v));
  dtb[idx] = dt;
}

// ---------------- causal depthwise conv + silu -> bf16 ----------------

__global__ void conv_silu_kernel(const float* __restrict__ zx, const float* __restrict__ cw,
                                 const float* __restrict__ cb, __hip_bfloat16* __restrict__ xbc) {
  int idx = blockIdx.x * 256 + threadIdx.x;
  if (idx >= BATCH * LSEQ * (CONVD / 4)) return;
  int c4 = idx % (CONVD / 4);
  int bl = idx / (CONVD / 4);
  int l = bl % LSEQ;
  int b = bl / LSEQ;
  int c0 = c4 * 4;
  const float* src = zx + (size_t)b * LSEQ * DPROJ_PAD + DI + c0;
  float4 w0 = *reinterpret_cast<const float4*>(cw + (c0 + 0) * 4);
  float4 w1 = *reinterpret_cast<const float4*>(cw + (c0 + 1) * 4);
  float4 w2 = *reinterpret_cast<const float4*>(cw + (c0 + 2) * 4);
  float4 w3 = *reinterpret_cast<const float4*>(cw + (c0 + 3) * 4);
  float4 acc = *reinterpret_cast<const float4*>(cb + c0);
  if (l >= 3) { float4 v = *reinterpret_cast<const float4*>(src + (size_t)(l - 3) * DPROJ_PAD);
    acc.x += w0.x * v.x; acc.y += w1.x * v.y; acc.z += w2.x * v.z; acc.w += w3.x * v.w; }
  if (l >= 2) { float4 v = *reinterpret_cast<const float4*>(src + (size_t)(l - 2) * DPROJ_PAD);
    acc.x += w0.y * v.x; acc.y += w1.y * v.y; acc.z += w2.y * v.z; acc.w += w3.y * v.w; }
  if (l >= 1) { float4 v = *reinterpret_cast<const float4*>(src + (size_t)(l - 1) * DPROJ_PAD);
    acc.x += w0.z * v.x; acc.y += w1.z * v.y; acc.z += w2.z * v.z; acc.w += w3.z * v.w; }
  { float4 v = *reinterpret_cast<const float4*>(src + (size_t)l * DPROJ_PAD);
    acc.x += w0.w * v.x; acc.y += w1.w * v.y; acc.z += w2.w * v.z; acc.w += w3.w * v.w; }
  acc.x = acc.x / (1.f + expf(-acc.x));
  acc.y = acc.y / (1.f + expf(-acc.y));
  acc.z = acc.z / (1.f + expf(-acc.z));
  acc.w = acc.w / (1.f + expf(-acc.w));
  *reinterpret_cast<ushort4*>(xbc + (size_t)bl * CONVD + c0) = pack4(acc.x, acc.y, acc.z, acc.w);
}

// ---------------- SSD pass 1: per-chunk MFMA (G^T -> L(+D) -> P -> Y, S) ----------------
// wg = (b,h,c), 4 waves. Big LDS tiles [rows][128] bf16, XOR-swizzled; B/C staged via
// global_load_lds with pre-swizzled bf16 source.

__global__ __launch_bounds__(256, 1)
void ssd_mfma_local(const __hip_bfloat16* __restrict__ bxc, const float* __restrict__ dtb,
                    const float* __restrict__ A_log, const float* __restrict__ Dparm,
                    float* __restrict__ y, __hip_bfloat16* __restrict__ sbuf,
                    float* __restrict__ pbuf, float* __restrict__ cumdecb) {
  __shared__ __hip_bfloat16 sB[128 * 128];   // B natural [t][n]
  __shared__ __hip_bfloat16 sC[128 * 128];   // C natural [t][n]; becomes P [t][s]
  __shared__ __hip_bfloat16 sBT[128 * 128];  // B'^T [n][t], scaled by w_t
  __shared__ __hip_bfloat16 sXT[64 * 128];   // X^T [p][t]
  __shared__ float scs[128], sdt[128], sw[128];

  const int bid = blockIdx.x;
  const int c = bid & (NCH - 1);
  const int h = (bid >> 4) & 31;
  const int b = bid >> 9;
  const int tid = threadIdx.x;
  const int w = tid >> 6, lane = tid & 63;
  const int t0 = c * QCH;
  const __hip_bfloat16* xc = bxc + (size_t)b * LSEQ * CONVD;
  const float a = expf(A_log[h]);
  const float Dh = Dparm[h];

  // ---- phase 0: cumsum of dt (wave 0), decay weights ----
  if (w == 0) {
    const float* dtp = dtb + ((size_t)b * LSEQ + t0) * NH + h;
    float v0 = dtp[lane * NH];
    float v1 = dtp[(64 + lane) * NH];
    float s0 = v0;
#pragma unroll
    for (int off = 1; off < 64; off <<= 1) {
      float tv = __shfl_up(s0, off);
      if (lane >= off) s0 += tv;
    }
    float T0 = __shfl(s0, 63);
    float s1 = v1;
#pragma unroll
    for (int off = 1; off < 64; off <<= 1) {
      float tv = __shfl_up(s1, off);
      if (lane >= off) s1 += tv;
    }
    float cs1 = s1 + T0;
    float Tt = __shfl(s1, 63) + T0;
    scs[lane] = s0;       scs[64 + lane] = cs1;
    sdt[lane] = v0;       sdt[64 + lane] = v1;
    sw[lane] = v0 * expf(-a * (Tt - s0));
    sw[64 + lane] = v1 * expf(-a * (Tt - cs1));
    cumdecb[bid * 128 + lane] = expf(-a * s0);
    cumdecb[bid * 128 + 64 + lane] = expf(-a * cs1);
    if (lane == 0) pbuf[bid] = expf(-a * Tt);
  }
  __syncthreads();

  // ---- phase 1: stage B, C (global_load_lds, pre-swizzled src), B'T + XT (scalar) ----
  {
    const int rsub = lane >> 4;       // 0..3 row within 4-row load
    const int ch = lane & 15;         // physical 16B chunk
#pragma unroll
    for (int j = 0; j < 8; ++j) {
      int row = w * 32 + j * 4 + rsub;
      int sc_ = ch ^ (row & 7);
      const __hip_bfloat16* pB = xc + (size_t)(t0 + row) * CONVD + DI + sc_ * 8;
      __builtin_amdgcn_global_load_lds((const AS1 void*)pB,
                                       (AS3 void*)(sB + (w * 32 + j * 4) * 128), 16, 0, 0);
      __builtin_amdgcn_global_load_lds((const AS1 void*)(pB + DSTATE),
                                       (AS3 void*)(sC + (w * 32 + j * 4) * 128), 16, 0, 0);
    }
  }
#pragma unroll
  for (int r = 0; r < 16; ++r) {
    int t = r * 8 + (tid >> 5);
    int n0 = (tid & 31) * 4;
    ushort4 bv = *reinterpret_cast<const ushort4*>(xc + (size_t)(t0 + t) * CONVD + DI + n0);
    float wt = sw[t];
    ldswr1u(sBT, n0 + 0, t, f2bf(bf2f(bv.x) * wt));
    ldswr1u(sBT, n0 + 1, t, f2bf(bf2f(bv.y) * wt));
    ldswr1u(sBT, n0 + 2, t, f2bf(bf2f(bv.z) * wt));
    ldswr1u(sBT, n0 + 3, t, f2bf(bf2f(bv.w) * wt));
  }
#pragma unroll
  for (int r = 0; r < 8; ++r) {
    int t = r * 16 + (tid >> 4);
    int p0 = (tid & 15) * 4;
    ushort4 xv = *reinterpret_cast<const ushort4*>(xc + (size_t)(t0 + t) * CONVD + h * HD + p0);
    ldswr1u(sXT, p0 + 0, t, xv.x);
    ldswr1u(sXT, p0 + 1, t, xv.y);
    ldswr1u(sXT, p0 + 2, t, xv.z);
    ldswr1u(sXT, p0 + 3, t, xv.w);
  }
  __syncthreads();

  const int fr = lane & 15;
  const int fk = (lane >> 4) * 8;
  const int rb = (lane >> 4) * 4;

  // ---- phase 2: G^T[s][t] = sum_n B[s][n] C[t][n]; wave quadrant 64x64 ----
  const int sR0 = (w >> 1) * 64, tC0 = (w & 1) * 64;
  f32x4 g[4][4];
#pragma unroll
  for (int m = 0; m < 4; ++m)
#pragma unroll
    for (int n = 0; n < 4; ++n) g[m][n] = (f32x4){0.f, 0.f, 0.f, 0.f};
  for (int kk = 0; kk < 128; kk += 32) {
    bf16x8 af[4], bfv[4];
#pragma unroll
    for (int m = 0; m < 4; ++m) af[m] = ldsfrag(sB, sR0 + m * 16 + fr, kk + fk);
#pragma unroll
    for (int n = 0; n < 4; ++n) bfv[n] = ldsfrag(sC, tC0 + n * 16 + fr, kk + fk);
#pragma unroll
    for (int m = 0; m < 4; ++m)
#pragma unroll
      for (int n = 0; n < 4; ++n)
        g[m][n] = __builtin_amdgcn_mfma_f32_16x16x32_bf16(af[m], bfv[n], g[m][n], 0, 0, 0);
  }
  __syncthreads();  // all waves done reading sB/sC

  // ---- apply causal decay mask L (+ D on diagonal), write P[t][s] into sC's slot ----
#pragma unroll
  for (int m = 0; m < 4; ++m) {
    int sb0 = sR0 + m * 16 + rb;
    float cs_s[4], dt_s[4];
#pragma unroll
    for (int j = 0; j < 4; ++j) { cs_s[j] = scs[sb0 + j]; dt_s[j] = sdt[sb0 + j]; }
#pragma unroll
    for (int n = 0; n < 4; ++n) {
      int tt = tC0 + n * 16 + fr;
      float cst = scs[tt];
      float vv[4];
#pragma unroll
      for (int j = 0; j < 4; ++j) {
        int s = sb0 + j;
        float e = expf(-a * (cst - cs_s[j])) * dt_s[j];
        float pv = (s <= tt) ? g[m][n][j] * e : 0.f;
        vv[j] = pv + ((s == tt) ? Dh : 0.f);
      }
      ldswr4(sC, tt, sb0, pack4(vv[0], vv[1], vv[2], vv[3]));
    }
  }
  __syncthreads();

  // ---- phase 3: Y[t][p] = sum_s P[t][s] X[s][p] (D folded into P diagonal) ----
  {
    int tR0 = w * 32;
    f32x4 yac[2][4];
#pragma unroll
    for (int m = 0; m < 2; ++m)
#pragma unroll
      for (int n = 0; n < 4; ++n) yac[m][n] = (f32x4){0.f, 0.f, 0.f, 0.f};
    for (int kk = 0; kk < 128; kk += 32) {
      bf16x8 af[2], bfv[4];
#pragma unroll
      for (int m = 0; m < 2; ++m) af[m] = ldsfrag(sC, tR0 + m * 16 + fr, kk + fk);
#pragma unroll
      for (int n = 0; n < 4; ++n) bfv[n] = ldsfrag(sXT, n * 16 + fr, kk + fk);
#pragma unroll
      for (int m = 0; m < 2; ++m)
#pragma unroll
        for (int n = 0; n < 4; ++n)
          yac[m][n] = __builtin_amdgcn_mfma_f32_16x16x32_bf16(af[m], bfv[n], yac[m][n], 0, 0, 0);
    }
#pragma unroll
    for (int m = 0; m < 2; ++m)
#pragma unroll
      for (int n = 0; n < 4; ++n) {
        int trow = tR0 + m * 16 + rb;
        int pc = n * 16 + fr;
        float* yp = y + ((size_t)b * LSEQ + t0 + trow) * DI + h * HD + pc;
#pragma unroll
        for (int j = 0; j < 4; ++j)
          yp[(size_t)j * DI] = yac[m][n][j];
      }
  }

  // ---- phase 4: S^T[p][n] = sum_t XT[p][t] B'T[n][t] -> sbuf[bid][p][n] ----
  {
    int pR0 = (w >> 1) * 32, nC0 = (w & 1) * 64;
    f32x4 sac[2][4];
#pragma unroll
    for (int m = 0; m < 2; ++m)
#pragma unroll
      for (int n = 0; n < 4; ++n) sac[m][n] = (f32x4){0.f, 0.f, 0.f, 0.f};
    for (int kk = 0; kk < 128; kk += 32) {
      bf16x8 af[2], bfv[4];
#pragma unroll
      for (int m = 0; m < 2; ++m) af[m] = ldsfrag(sXT, pR0 + m * 16 + fr, kk + fk);
#pragma unroll
      for (int n = 0; n < 4; ++n) bfv[n] = ldsfrag(sBT, nC0 + n * 16 + fr, kk + fk);
#pragma unroll
      for (int m = 0; m < 2; ++m)
#pragma unroll
        for (int n = 0; n < 4; ++n)
          sac[m][n] = __builtin_amdgcn_mfma_f32_16x16x32_bf16(af[m], bfv[n], sac[m][n], 0, 0, 0);
    }
    __hip_bfloat16* sg = sbuf + (size_t)bid * 8192;
#pragma unroll
    for (int m = 0; m < 2; ++m)
#pragma unroll
      for (int n = 0; n < 4; ++n) {
        int p = pR0 + m * 16 + rb;
        int nn = nC0 + n * 16 + fr;
#pragma unroll
        for (int j = 0; j < 4; ++j)
          sg[(size_t)(p + j) * 128 + nn] = __float2bfloat16(sac[m][n][j]);
      }
  }
}

// ---------------- SSD pass 2: propagate chunk states ----------------

__global__ void ssd_prop_kernel(__hip_bfloat16* __restrict__ sbuf,
                                const float* __restrict__ pbuf) {
  int idx = blockIdx.x * 256 + threadIdx.x;   // 64 * 8192
  int bh = idx >> 13;
  int e = idx & 8191;
  __hip_bfloat16* base = sbuf + (size_t)bh * NCH * 8192 + e;
  const float* pb = pbuf + bh * NCH;
  float hs = 0.f;
  for (int cc = 0; cc < NCH; ++cc) {
    float sc = __bfloat162float(base[(size_t)cc * 8192]);
    base[(size_t)cc * 8192] = __float2bfloat16(hs);
    hs = fmaf(hs, pb[cc], sc);
  }
}

// ---------------- SSD pass 3: Y += diag(cumdec) * C @ h_start (MFMA) ----------------

__global__ __launch_bounds__(256)
void ssd_mfma_corr(const __hip_bfloat16* __restrict__ bxc, const __hip_bfloat16* __restrict__ sbuf,
                   const float* __restrict__ cumdecb, float* __restrict__ y) {
  __shared__ __hip_bfloat16 sC[128 * 128];
  __shared__ __hip_bfloat16 sH[64 * 128];
  __shared__ float scd[128];
  const int bid = blockIdx.x;
  const int c = bid & (NCH - 1);
  if (c == 0) return;  // block-uniform exit
  const int h = (bid >> 4) & 31;
  const int b = bid >> 9;
  const int tid = threadIdx.x;
  const int w = tid >> 6, lane = tid & 63;
  const int t0 = c * QCH;
  const __hip_bfloat16* xc = bxc + (size_t)b * LSEQ * CONVD;

  {
    const int rsub = lane >> 4;
    const int ch = lane & 15;
#pragma unroll
    for (int j = 0; j < 8; ++j) {
      int row = w * 32 + j * 4 + rsub;
      int sc_ = ch ^ (row & 7);
      const __hip_bfloat16* pC = xc + (size_t)(t0 + row) * CONVD + DI + DSTATE + sc_ * 8;
      __builtin_amdgcn_global_load_lds((const AS1 void*)pC,
                                       (AS3 void*)(sC + (w * 32 + j * 4) * 128), 16, 0, 0);
    }
#pragma unroll
    for (int j = 0; j < 4; ++j) {
      int row = w * 16 + j * 4 + rsub;
      int sc_ = ch ^ (row & 7);
      const __hip_bfloat16* pH = sbuf + (size_t)bid * 8192 + row * 128 + sc_ * 8;
      __builtin_amdgcn_global_load_lds((const AS1 void*)pH,
                                       (AS3 void*)(sH + (w * 16 + j * 4) * 128), 16, 0, 0);
    }
  }
  if (tid < 128) scd[tid] = cumdecb[bid * 128 + tid];
  __syncthreads();

  const int fr = lane & 15;
  const int fk = (lane >> 4) * 8;
  const int rb = (lane >> 4) * 4;
  int tR0 = w * 32;
  f32x4 ac[2][4];
#pragma unroll
  for (int m = 0; m < 2; ++m)
#pragma unroll
    for (int n = 0; n < 4; ++n) ac[m][n] = (f32x4){0.f, 0.f, 0.f, 0.f};
  for (int kk = 0; kk < 128; kk += 32) {
    bf16x8 af[2], bfv[4];
#pragma unroll
    for (int m = 0; m < 2; ++m) af[m] = ldsfrag(sC, tR0 + m * 16 + fr, kk + fk);
#pragma unroll
    for (int n = 0; n < 4; ++n) bfv[n] = ldsfrag(sH, n * 16 + fr, kk + fk);
#pragma unroll
    for (int m = 0; m < 2; ++m)
#pragma unroll
      for (int n = 0; n < 4; ++n)
        ac[m][n] = __builtin_amdgcn_mfma_f32_16x16x32_bf16(af[m], bfv[n], ac[m][n], 0, 0, 0);
  }
#pragma unroll
  for (int m = 0; m < 2; ++m)
#pragma unroll
    for (int n = 0; n < 4; ++n) {
      int trow = tR0 + m * 16 + rb;
      int pc = n * 16 + fr;
      float* yp = y + ((size_t)b * LSEQ + t0 + trow) * DI + h * HD + pc;
#pragma unroll
      for (int j = 0; j < 4; ++j)
        yp[(size_t)j * DI] += scd[trow + j] * ac[m][n][j];
    }
}

// ---------------- gating + RMS norm -> bf16 ----------------

__global__ __launch_bounds__(256)
void gate_rms_kernel(const float* __restrict__ y, const float* __restrict__ zx,
                     const float* __restrict__ nw, __hip_bfloat16* __restrict__ g) {
  int row = blockIdx.x;
  int t = threadIdx.x;
  const float* yr = y + (size_t)row * DI;
  const float* zr = zx + (size_t)row * DPROJ_PAD;
  float v[8];
  float ss = 0.f;
#pragma unroll
  for (int j = 0; j < 8; ++j) {
    int c = j * 256 + t;
    float z = zr[c];
    float vv = yr[c] * (z / (1.f + expf(-z)));
    v[j] = vv;
    ss += vv * vv;
  }
#pragma unroll
  for (int off = 32; off; off >>= 1) ss += __shfl_down(ss, off);
  __shared__ float red[4];
  if ((t & 63) == 0) red[t >> 6] = ss;
  __syncthreads();
  float tot = red[0] + red[1] + red[2] + red[3];
  float rstd = rsqrtf(tot * (1.f / DI) + EPSV);
#pragma unroll
  for (int j = 0; j < 8; ++j) {
    int c = j * 256 + t;
    g[(size_t)row * DI + c] = __float2bfloat16(v[j] * rstd * nw[c]);
  }
}

// ---------------- final RMS + residual ----------------

__global__ __launch_bounds__(256)
void final_rms_add(const float* __restrict__ o1, const float* __restrict__ x,
                   float* __restrict__ out) {
  int row = blockIdx.x;
  int t = threadIdx.x;
  const float* orow = o1 + (size_t)row * DMODEL;
  float v[4];
  float ss = 0.f;
#pragma unroll
  for (int j = 0; j < 4; ++j) {
    int c = j * 256 + t;
    float o = orow[c];
    v[j] = o;
    ss += o * o;
  }
#pragma unroll
  for (int off = 32; off; off >>= 1) ss += __shfl_down(ss, off);
  __shared__ float red[4];
  if ((t & 63) == 0) red[t >> 6] = ss;
  __syncthreads();
  float tot = red[0] + red[1] + red[2] + red[3];
  float rstd = rsqrtf(tot * (1.f / DMODEL) + EPSV);
#pragma unroll
  for (int j = 0; j < 4; ++j) {
    int c = j * 256 + t;
    out[(size_t)row * DMODEL + c] = v[j] * rstd + x[(size_t)row * DMODEL + c];
  }
}

// ---------------- launch ----------------

extern "C" void kernel_launch(void* const* d_in, const int* in_sizes, int n_in,
                              void* d_out, int out_size, void* d_ws, size_t ws_size,
                              hipStream_t stream) {
  const float* x       = (const float*)d_in[0];
  const float* W_in    = (const float*)d_in[1];
  const float* conv_w  = (const float*)d_in[2];
  const float* conv_b  = (const float*)d_in[3];
  const float* dt_bias = (const float*)d_in[4];
  const float* A_log   = (const float*)d_in[5];
  const float* Dp      = (const float*)d_in[6];
  const float* norm_w  = (const float*)d_in[7];
  const float* W_out   = (const float*)d_in[8];
  float* out = (float*)d_out;

  float* zx   = (float*)d_ws;                               // 4096 x 4480 f32
  float* xbcF = zx + (size_t)18350080;                      // slot (xbc bf16 lives here)
  __hip_bfloat16* xbc = (__hip_bfloat16*)xbcF;              // 4096 x 2304 bf16
  float* ybuf = xbcF + (size_t)9437184;                     // 4096 x 2048 f32
  float* dtb  = ybuf + (size_t)8388608;                     // 131072
  float* cumdecb = dtb + (size_t)131072;                    // 131072 (1024 x 128)
  __hip_bfloat16* xbf   = (__hip_bfloat16*)(cumdecb + 131072); // 4096x1024
  __hip_bfloat16* wtin  = xbf + (size_t)4194304;               // 4480x1024
  __hip_bfloat16* wtout = wtin + (size_t)4587520;              // 1024x2048
  float* pbuf = (float*)(wtout + (size_t)2097152);             // 1024 floats
  __hip_bfloat16* sbuf = xbf;  // overlay: xbf/wtin dead after GEMM1
  __hip_bfloat16* gbf = xbf;   // overlay: sbuf dead after ssd_mfma_corr
  float* o1 = xbcF;            // overlay: xbc dead after ssd_mfma_corr

  f32_to_bf16_kernel<<<4096, 256, 0, stream>>>(x, xbf, 1048576);
  transpose_f32_bf16<<<dim3(140, 32), dim3(32, 8), 0, stream>>>(W_in, wtin, 1024, 4384, 4480);
  transpose_f32_bf16<<<dim3(32, 64), dim3(32, 8), 0, stream>>>(W_out, wtout, 2048, 1024, 1024);

  gemm_bt2<<<1120, 256, 0, stream>>>(xbf, wtin, zx, 4096, 4480, 1024, 35, 140);

  dtdecay_kernel<<<512, 256, 0, stream>>>(zx, dt_bias, dtb);
  conv_silu_kernel<<<9216, 256, 0, stream>>>(zx, conv_w, conv_b, xbc);

  ssd_mfma_local<<<1024, 256, 0, stream>>>(xbc, dtb, A_log, Dp, ybuf, sbuf, pbuf, cumdecb);
  ssd_prop_kernel<<<2048, 256, 0, stream>>>(sbuf, pbuf);
  ssd_mfma_corr<<<1024, 256, 0, stream>>>(xbc, sbuf, cumdecb, ybuf);

  gate_rms_kernel<<<4096, 256, 0, stream>>>(ybuf, zx, norm_w, gbf);

  gemm_bt2<<<256, 256, 0, stream>>>(gbf, wtout, o1, 4096, 1024, 2048, 8, 32);

  final_rms_add<<<4096, 256, 0, stream>>>(o1, x, out);
}

// Round 8
// 222.524 us; speedup vs baseline: 2.0522x; 1.1293x over previous
//
#include <hip/hip_runtime.h>
#include <hip/hip_bf16.h>

#define DMODEL 1024
#define DI     2048
#define DSTATE 128
#define NH     32
#define HD     64
#define CONVD  2304
#define LSEQ   2048
#define BATCH  2
#define DPROJ  4384
#define DPROJ_PAD 4480
#define EPSV   1e-5f
#define QCH    128
#define NCH    16

#define AS1 __attribute__((address_space(1)))
#define AS3 __attribute__((address_space(3)))

typedef __attribute__((ext_vector_type(8))) short bf16x8;
typedef __attribute__((ext_vector_type(4))) float f32x4;

union U4 { ushort4 u; __hip_bfloat16 h[4]; };

__device__ __forceinline__ float bf2f(unsigned short u) {
  union { unsigned int i; float f; } c; c.i = ((unsigned)u) << 16; return c.f;
}
__device__ __forceinline__ ushort4 pack4(float x0, float x1, float x2, float x3) {
  U4 p;
  p.h[0] = __float2bfloat16(x0); p.h[1] = __float2bfloat16(x1);
  p.h[2] = __float2bfloat16(x2); p.h[3] = __float2bfloat16(x3);
  return p.u;
}

// ---- swizzled LDS helpers: [rows][128] bf16 tiles (256B rows), byte ^= (row&7)<<4 ----
__device__ __forceinline__ bf16x8 ldsfrag(const __hip_bfloat16* base, int row, int ke) {
  int byte = row * 256 + ke * 2;
  byte ^= (row & 7) << 4;
  return *reinterpret_cast<const bf16x8*>(reinterpret_cast<const char*>(base) + byte);
}
__device__ __forceinline__ void ldswr4(__hip_bfloat16* base, int row, int col4, ushort4 v) {
  int byte = row * 256 + col4 * 2;
  byte ^= (row & 7) << 4;
  *reinterpret_cast<ushort4*>(reinterpret_cast<char*>(base) + byte) = v;
}
__device__ __forceinline__ void ldswr8(__hip_bfloat16* base, int row, int colElem,
                                       unsigned lo, unsigned hi) {
  int byte = row * 256 + colElem * 2;
  byte ^= (row & 7) << 4;
  uint2 v; v.x = lo; v.y = hi;
  *reinterpret_cast<uint2*>(reinterpret_cast<char*>(base) + byte) = v;
}
// ---- swizzled helpers for [rows][64] bf16 tiles (128B rows), same XOR ----
__device__ __forceinline__ bf16x8 frag64(const __hip_bfloat16* base, int row, int ke) {
  int byte = row * 128 + ke * 2;
  byte ^= (row & 7) << 4;
  return *reinterpret_cast<const bf16x8*>(reinterpret_cast<const char*>(base) + byte);
}

// ---- in-register 4x4 u16 transpose across a quad (lanes ql=0..3) ----
// input: lane ql holds row ql as (a01, a23); output: lane ql holds column ql.
__device__ __forceinline__ void quadtr(unsigned a01, unsigned a23, int ql,
                                       unsigned& w01, unsigned& w23) {
  unsigned y01 = __shfl_xor((int)a01, 1), y23 = __shfl_xor((int)a23, 1);
  unsigned c01 = (ql & 1) ? ((y01 >> 16) | (a01 & 0xFFFF0000u))
                          : ((a01 & 0xFFFFu) | (y01 << 16));
  unsigned c23 = (ql & 1) ? ((y23 >> 16) | (a23 & 0xFFFF0000u))
                          : ((a23 & 0xFFFFu) | (y23 << 16));
  unsigned d01 = __shfl_xor((int)c01, 2), d23 = __shfl_xor((int)c23, 2);
  w01 = (ql & 2) ? d23 : c01;
  w23 = (ql & 2) ? c23 : d01;
}

// ---------------- conversion kernels ----------------

__global__ void f32_to_bf16_kernel(const float* __restrict__ in,
                                   __hip_bfloat16* __restrict__ out, int n4) {
  int i = blockIdx.x * 256 + threadIdx.x;
  if (i >= n4) return;
  float4 v = reinterpret_cast<const float4*>(in)[i];
  reinterpret_cast<ushort4*>(out)[i] = pack4(v.x, v.y, v.z, v.w);
}

__global__ void transpose_f32_bf16(const float* __restrict__ in,
                                   __hip_bfloat16* __restrict__ out,
                                   int R, int C, int Cpad) {
  __shared__ float tile[32][33];
  int n0 = blockIdx.x * 32, k0 = blockIdx.y * 32;
  int tx = threadIdx.x, ty = threadIdx.y;  // (32,8)
#pragma unroll
  for (int j = 0; j < 32; j += 8) {
    int k = k0 + ty + j, n = n0 + tx;
    tile[ty + j][tx] = (n < C) ? in[(size_t)k * C + n] : 0.f;
  }
  __syncthreads();
#pragma unroll
  for (int j = 0; j < 32; j += 8) {
    int n = n0 + ty + j, k = k0 + tx;
    if (n < Cpad) out[(size_t)n * R + k] = __float2bfloat16(tile[tx][ty + j]);
  }
}

// ---------------- GEMM: 128x128 tile, BK=64, dbuf 2-phase, T2 swizzle ----------------
// C(MxN,f32) = A(MxK,bf16)*Bt(NxK,bf16)^T.  M/128 must be 32 (8 XCD x 4 panels):
// XCD owns 4 consecutive M-panels and iterates m-fastest so B-panels stay L2-hot.

__global__ __launch_bounds__(256, 2)
void gemm_bt2(const __hip_bfloat16* __restrict__ A,
              const __hip_bfloat16* __restrict__ Bt,
              float* __restrict__ C,
              int M, int N, int K) {
  __shared__ __hip_bfloat16 smA[2][128 * 64];
  __shared__ __hip_bfloat16 smB[2][128 * 64];
  const int xcd = blockIdx.x & 7;
  const int i = blockIdx.x >> 3;
  const int bm = ((xcd << 2) + (i & 3)) * 128;
  const int bn = (i >> 2) * 128;
  const int t = threadIdx.x;
  const int w = t >> 6, lane = t & 63;
  const int wr = (w >> 1) * 64, wc = (w & 1) * 64;
  const int fr = lane & 15, fk = (lane >> 4) * 8;
  const int srow = lane >> 3;
  const int scol = ((lane & 7) ^ srow) * 8;

  f32x4 acc[4][4];
#pragma unroll
  for (int m = 0; m < 4; ++m)
#pragma unroll
    for (int n = 0; n < 4; ++n) acc[m][n] = (f32x4){0.f, 0.f, 0.f, 0.f};

  const __hip_bfloat16* aSrc = A + (size_t)(bm + srow) * K + scol;
  const __hip_bfloat16* bSrc = Bt + (size_t)(bn + srow) * K + scol;

  auto STAGE = [&](int buf, int k0) {
#pragma unroll
    for (int i2 = 0; i2 < 4; ++i2) {
      int ro = w * 32 + i2 * 8;
      __builtin_amdgcn_global_load_lds((const AS1 void*)(aSrc + (size_t)ro * K + k0),
                                       (AS3 void*)(&smA[buf][ro * 64]), 16, 0, 0);
      __builtin_amdgcn_global_load_lds((const AS1 void*)(bSrc + (size_t)ro * K + k0),
                                       (AS3 void*)(&smB[buf][ro * 64]), 16, 0, 0);
    }
  };

  STAGE(0, 0);
  __syncthreads();
  const int nt = K >> 6;
  int cur = 0;
  for (int kt = 0; kt < nt; ++kt) {
    if (kt + 1 < nt) STAGE(cur ^ 1, (kt + 1) << 6);
#pragma unroll
    for (int kk = 0; kk < 64; kk += 32) {
      bf16x8 af[4], bfv[4];
#pragma unroll
      for (int m = 0; m < 4; ++m) af[m] = frag64(&smA[cur][0], wr + m * 16 + fr, kk + fk);
#pragma unroll
      for (int n = 0; n < 4; ++n) bfv[n] = frag64(&smB[cur][0], wc + n * 16 + fr, kk + fk);
#pragma unroll
      for (int m = 0; m < 4; ++m)
#pragma unroll
        for (int n = 0; n < 4; ++n)
          acc[m][n] = __builtin_amdgcn_mfma_f32_16x16x32_bf16(af[m], bfv[n], acc[m][n], 0, 0, 0);
    }
    __syncthreads();
    cur ^= 1;
  }

  const int r4 = (lane >> 4) * 4;
  const int cn = lane & 15;
#pragma unroll
  for (int m = 0; m < 4; ++m)
#pragma unroll
    for (int n = 0; n < 4; ++n) {
      int row = bm + wr + m * 16 + r4;
      int col = bn + wc + n * 16 + cn;
      float* cp = C + (size_t)row * N + col;
#pragma unroll
      for (int j = 0; j < 4; ++j) cp[(size_t)j * N] = acc[m][n][j];
    }
}

// ---------------- dt precompute ----------------

__global__ void dtdecay_kernel(const float* __restrict__ zx, const float* __restrict__ dt_bias,
                               float* __restrict__ dtb) {
  int idx = blockIdx.x * 256 + threadIdx.x;
  if (idx >= BATCH * LSEQ * NH) return;
  int h = idx & 31;
  int bl = idx >> 5;
  float v = zx[(size_t)bl * DPROJ_PAD + (DI + CONVD) + h] + dt_bias[h];
  float dt = (v > 20.f) ? v : log1pf(expf(v));
  dtb[idx] = dt;
}

// ---------------- per-chunk cumsum / decay stats (one wave per (b,h,c)) ----------------

__global__ __launch_bounds__(256)
void chunk_stats_kernel(const float* __restrict__ dtb, const float* __restrict__ A_log,
                        float* __restrict__ csb, float* __restrict__ dtc,
                        float* __restrict__ swb, float* __restrict__ cumdecb,
                        float* __restrict__ pbuf) {
  int w = threadIdx.x >> 6, lane = threadIdx.x & 63;
  int bid = blockIdx.x * 4 + w;           // 0..1023
  int c = bid & (NCH - 1);
  int h = (bid >> 4) & 31;
  int b = bid >> 9;
  int t0 = c * QCH;
  float a = expf(A_log[h]);
  const float* dtp = dtb + ((size_t)b * LSEQ + t0) * NH + h;
  float v0 = dtp[lane * NH];
  float v1 = dtp[(64 + lane) * NH];
  float s0 = v0;
#pragma unroll
  for (int off = 1; off < 64; off <<= 1) {
    float tv = __shfl_up(s0, off);
    if (lane >= off) s0 += tv;
  }
  float T0 = __shfl(s0, 63);
  float s1 = v1;
#pragma unroll
  for (int off = 1; off < 64; off <<= 1) {
    float tv = __shfl_up(s1, off);
    if (lane >= off) s1 += tv;
  }
  float cs1 = s1 + T0;
  float Tt = __shfl(s1, 63) + T0;
  size_t base = (size_t)bid * 128;
  csb[base + lane] = s0;        csb[base + 64 + lane] = cs1;
  dtc[base + lane] = v0;        dtc[base + 64 + lane] = v1;
  swb[base + lane] = v0 * expf(-a * (Tt - s0));
  swb[base + 64 + lane] = v1 * expf(-a * (Tt - cs1));
  cumdecb[base + lane] = expf(-a * s0);
  cumdecb[base + 64 + lane] = expf(-a * cs1);
  if (lane == 0) pbuf[bid] = expf(-a * Tt);
}

// ---------------- causal depthwise conv + silu -> bf16 ----------------

__global__ void conv_silu_kernel(const float* __restrict__ zx, const float* __restrict__ cw,
                                 const float* __restrict__ cb, __hip_bfloat16* __restrict__ xbc) {
  int idx = blockIdx.x * 256 + threadIdx.x;
  if (idx >= BATCH * LSEQ * (CONVD / 4)) return;
  int c4 = idx % (CONVD / 4);
  int bl = idx / (CONVD / 4);
  int l = bl % LSEQ;
  int b = bl / LSEQ;
  int c0 = c4 * 4;
  const float* src = zx + (size_t)b * LSEQ * DPROJ_PAD + DI + c0;
  float4 w0 = *reinterpret_cast<const float4*>(cw + (c0 + 0) * 4);
  float4 w1 = *reinterpret_cast<const float4*>(cw + (c0 + 1) * 4);
  float4 w2 = *reinterpret_cast<const float4*>(cw + (c0 + 2) * 4);
  float4 w3 = *reinterpret_cast<const float4*>(cw + (c0 + 3) * 4);
  float4 acc = *reinterpret_cast<const float4*>(cb + c0);
  if (l >= 3) { float4 v = *reinterpret_cast<const float4*>(src + (size_t)(l - 3) * DPROJ_PAD);
    acc.x += w0.x * v.x; acc.y += w1.x * v.y; acc.z += w2.x * v.z; acc.w += w3.x * v.w; }
  if (l >= 2) { float4 v = *reinterpret_cast<const float4*>(src + (size_t)(l - 2) * DPROJ_PAD);
    acc.x += w0.y * v.x; acc.y += w1.y * v.y; acc.z += w2.y * v.z; acc.w += w3.y * v.w; }
  if (l >= 1) { float4 v = *reinterpret_cast<const float4*>(src + (size_t)(l - 1) * DPROJ_PAD);
    acc.x += w0.z * v.x; acc.y += w1.z * v.y; acc.z += w2.z * v.z; acc.w += w3.z * v.w; }
  { float4 v = *reinterpret_cast<const float4*>(src + (size_t)l * DPROJ_PAD);
    acc.x += w0.w * v.x; acc.y += w1.w * v.y; acc.z += w2.w * v.z; acc.w += w3.w * v.w; }
  acc.x = acc.x / (1.f + expf(-acc.x));
  acc.y = acc.y / (1.f + expf(-acc.y));
  acc.z = acc.z / (1.f + expf(-acc.z));
  acc.w = acc.w / (1.f + expf(-acc.w));
  *reinterpret_cast<ushort4*>(xbc + (size_t)bl * CONVD + c0) = pack4(acc.x, acc.y, acc.z, acc.w);
}

// ---------------- SSD pass 1: per-chunk MFMA ----------------
// LDS 80KB exactly -> 2 blocks/CU. T_B: B -> P; T_C: C -> Bw^T; T_X: X^T.

__global__ __launch_bounds__(256, 2)
void ssd_mfma_local(const __hip_bfloat16* __restrict__ bxc,
                    const float* __restrict__ csb, const float* __restrict__ dtc,
                    const float* __restrict__ swb,
                    const float* __restrict__ A_log, const float* __restrict__ Dparm,
                    float* __restrict__ y, __hip_bfloat16* __restrict__ sbuf) {
  __shared__ __hip_bfloat16 T_B[128 * 128];
  __shared__ __hip_bfloat16 T_C[128 * 128];
  __shared__ __hip_bfloat16 T_X[64 * 128];

  const int bid = blockIdx.x;
  const int c = bid & (NCH - 1);
  const int h = (bid >> 4) & 31;
  const int b = bid >> 9;
  const int tid = threadIdx.x;
  const int w = tid >> 6, lane = tid & 63;
  const int q = lane >> 2, ql = lane & 3;
  const int t0 = c * QCH;
  const __hip_bfloat16* xc = bxc + (size_t)b * LSEQ * CONVD;
  const float a = expf(A_log[h]);
  const float Dh = Dparm[h];

  // ---- stage B, C via global_load_lds (pre-swizzled source chunks) ----
  {
    const int rsub = lane >> 4;
    const int ch = lane & 15;
#pragma unroll
    for (int j = 0; j < 8; ++j) {
      int row = w * 32 + j * 4 + rsub;
      int sc_ = ch ^ (row & 7);
      const __hip_bfloat16* pB = xc + (size_t)(t0 + row) * CONVD + DI + sc_ * 8;
      __builtin_amdgcn_global_load_lds((const AS1 void*)pB,
                                       (AS3 void*)(T_B + (w * 32 + j * 4) * 128), 16, 0, 0);
      __builtin_amdgcn_global_load_lds((const AS1 void*)(pB + DSTATE),
                                       (AS3 void*)(T_C + (w * 32 + j * 4) * 128), 16, 0, 0);
    }
  }
  // ---- stage X^T via quad transpose (8B swizzled writes) ----
#pragma unroll
  for (int r = 0; r < 8; ++r) {
    int gidx = w * 128 + q * 8 + r;     // 0..511
    int tb = (gidx & 31) * 4;
    int pb = (gidx >> 5) * 4;
    int t = tb + ql;
    ushort4 xv = *reinterpret_cast<const ushort4*>(xc + (size_t)(t0 + t) * CONVD + h * HD + pb);
    unsigned a01 = (unsigned)xv.x | ((unsigned)xv.y << 16);
    unsigned a23 = (unsigned)xv.z | ((unsigned)xv.w << 16);
    unsigned w01, w23;
    quadtr(a01, a23, ql, w01, w23);
    ldswr8(T_X, pb + ql, tb, w01, w23);
  }
  __syncthreads();

  const int fr = lane & 15;
  const int fk = (lane >> 4) * 8;
  const int rb = (lane >> 4) * 4;

  // ---- phase 2: G^T[s][t] = sum_n B[s][n] C[t][n]; wave quadrant 64x64 ----
  const int sR0 = (w >> 1) * 64, tC0 = (w & 1) * 64;
  f32x4 g[4][4];
#pragma unroll
  for (int m = 0; m < 4; ++m)
#pragma unroll
    for (int n = 0; n < 4; ++n) g[m][n] = (f32x4){0.f, 0.f, 0.f, 0.f};
  for (int kk = 0; kk < 128; kk += 32) {
    bf16x8 af[4], bfv[4];
#pragma unroll
    for (int m = 0; m < 4; ++m) af[m] = ldsfrag(T_B, sR0 + m * 16 + fr, kk + fk);
#pragma unroll
    for (int n = 0; n < 4; ++n) bfv[n] = ldsfrag(T_C, tC0 + n * 16 + fr, kk + fk);
#pragma unroll
    for (int m = 0; m < 4; ++m)
#pragma unroll
      for (int n = 0; n < 4; ++n)
        g[m][n] = __builtin_amdgcn_mfma_f32_16x16x32_bf16(af[m], bfv[n], g[m][n], 0, 0, 0);
  }
  __syncthreads();  // all waves done reading T_B/T_C

  // ---- mask L (+D diag) -> write P[t][s] into T_B; build Bw^T into T_C ----
  {
    const float* csp = csb + (size_t)bid * 128;
    const float* dtp = dtc + (size_t)bid * 128;
#pragma unroll
    for (int m = 0; m < 4; ++m) {
      int sb0 = sR0 + m * 16 + rb;
      float cs_s[4], dt_s[4];
#pragma unroll
      for (int j = 0; j < 4; ++j) { cs_s[j] = csp[sb0 + j]; dt_s[j] = dtp[sb0 + j]; }
#pragma unroll
      for (int n = 0; n < 4; ++n) {
        int tt = tC0 + n * 16 + fr;
        float cst = csp[tt];
        float vv[4];
#pragma unroll
        for (int j = 0; j < 4; ++j) {
          int s = sb0 + j;
          float e = __expf(-a * (cst - cs_s[j])) * dt_s[j];
          float pv = (s <= tt) ? g[m][n][j] * e : 0.f;
          vv[j] = pv + ((s == tt) ? Dh : 0.f);
        }
        ldswr4(T_B, tt, sb0, pack4(vv[0], vv[1], vv[2], vv[3]));
      }
    }
    // Bw^T build: scale rows by w_t, quad-transpose, 8B writes
    const float* swp = swb + (size_t)bid * 128;
#pragma unroll
    for (int r = 0; r < 16; ++r) {
      int gidx = w * 256 + q * 16 + r;   // 0..1023
      int tb = (gidx & 31) * 4;
      int nb = (gidx >> 5) * 4;
      int t = tb + ql;
      ushort4 bv = *reinterpret_cast<const ushort4*>(xc + (size_t)(t0 + t) * CONVD + DI + nb);
      float wt = swp[t];
      ushort4 sv = pack4(bf2f(bv.x) * wt, bf2f(bv.y) * wt, bf2f(bv.z) * wt, bf2f(bv.w) * wt);
      unsigned a01 = (unsigned)sv.x | ((unsigned)sv.y << 16);
      unsigned a23 = (unsigned)sv.z | ((unsigned)sv.w << 16);
      unsigned w01, w23;
      quadtr(a01, a23, ql, w01, w23);
      ldswr8(T_C, nb + ql, tb, w01, w23);
    }
  }
  __syncthreads();

  // ---- phase 3: Y[t][p] = sum_s P[t][s] X[s][p] ----
  {
    int tR0 = w * 32;
    f32x4 yac[2][4];
#pragma unroll
    for (int m = 0; m < 2; ++m)
#pragma unroll
      for (int n = 0; n < 4; ++n) yac[m][n] = (f32x4){0.f, 0.f, 0.f, 0.f};
    for (int kk = 0; kk < 128; kk += 32) {
      bf16x8 af[2], bfv[4];
#pragma unroll
      for (int m = 0; m < 2; ++m) af[m] = ldsfrag(T_B, tR0 + m * 16 + fr, kk + fk);
#pragma unroll
      for (int n = 0; n < 4; ++n) bfv[n] = ldsfrag(T_X, n * 16 + fr, kk + fk);
#pragma unroll
      for (int m = 0; m < 2; ++m)
#pragma unroll
        for (int n = 0; n < 4; ++n)
          yac[m][n] = __builtin_amdgcn_mfma_f32_16x16x32_bf16(af[m], bfv[n], yac[m][n], 0, 0, 0);
    }
#pragma unroll
    for (int m = 0; m < 2; ++m)
#pragma unroll
      for (int n = 0; n < 4; ++n) {
        int trow = tR0 + m * 16 + rb;
        int pc = n * 16 + fr;
        float* yp = y + ((size_t)b * LSEQ + t0 + trow) * DI + h * HD + pc;
#pragma unroll
        for (int j = 0; j < 4; ++j)
          yp[(size_t)j * DI] = yac[m][n][j];
      }
  }

  // ---- phase 4: S^T[p][n] = sum_t XT[p][t] BwT[n][t] -> sbuf[bid][p][n] ----
  {
    int pR0 = (w >> 1) * 32, nC0 = (w & 1) * 64;
    f32x4 sac[2][4];
#pragma unroll
    for (int m = 0; m < 2; ++m)
#pragma unroll
      for (int n = 0; n < 4; ++n) sac[m][n] = (f32x4){0.f, 0.f, 0.f, 0.f};
    for (int kk = 0; kk < 128; kk += 32) {
      bf16x8 af[2], bfv[4];
#pragma unroll
      for (int m = 0; m < 2; ++m) af[m] = ldsfrag(T_X, pR0 + m * 16 + fr, kk + fk);
#pragma unroll
      for (int n = 0; n < 4; ++n) bfv[n] = ldsfrag(T_C, nC0 + n * 16 + fr, kk + fk);
#pragma unroll
      for (int m = 0; m < 2; ++m)
#pragma unroll
        for (int n = 0; n < 4; ++n)
          sac[m][n] = __builtin_amdgcn_mfma_f32_16x16x32_bf16(af[m], bfv[n], sac[m][n], 0, 0, 0);
    }
    __hip_bfloat16* sg = sbuf + (size_t)bid * 8192;
#pragma unroll
    for (int m = 0; m < 2; ++m)
#pragma unroll
      for (int n = 0; n < 4; ++n) {
        int p = pR0 + m * 16 + rb;
        int nn = nC0 + n * 16 + fr;
#pragma unroll
        for (int j = 0; j < 4; ++j)
          sg[(size_t)(p + j) * 128 + nn] = __float2bfloat16(sac[m][n][j]);
      }
  }
}

// ---------------- SSD pass 2: propagate chunk states ----------------

__global__ void ssd_prop_kernel(__hip_bfloat16* __restrict__ sbuf,
                                const float* __restrict__ pbuf) {
  int idx = blockIdx.x * 256 + threadIdx.x;   // 64 * 8192
  int bh = idx >> 13;
  int e = idx & 8191;
  __hip_bfloat16* base = sbuf + (size_t)bh * NCH * 8192 + e;
  const float* pb = pbuf + bh * NCH;
  float hs = 0.f;
  for (int cc = 0; cc < NCH; ++cc) {
    float sc = __bfloat162float(base[(size_t)cc * 8192]);
    base[(size_t)cc * 8192] = __float2bfloat16(hs);
    hs = fmaf(hs, pb[cc], sc);
  }
}

// ---------------- SSD pass 3: Y += diag(cumdec) * C @ h_start (MFMA) ----------------

__global__ __launch_bounds__(256)
void ssd_mfma_corr(const __hip_bfloat16* __restrict__ bxc, const __hip_bfloat16* __restrict__ sbuf,
                   const float* __restrict__ cumdecb, float* __restrict__ y) {
  __shared__ __hip_bfloat16 sC[128 * 128];
  __shared__ __hip_bfloat16 sH[64 * 128];
  __shared__ float scd[128];
  const int bid = blockIdx.x;
  const int c = bid & (NCH - 1);
  if (c == 0) return;  // block-uniform exit
  const int h = (bid >> 4) & 31;
  const int b = bid >> 9;
  const int tid = threadIdx.x;
  const int w = tid >> 6, lane = tid & 63;
  const int t0 = c * QCH;
  const __hip_bfloat16* xc = bxc + (size_t)b * LSEQ * CONVD;

  {
    const int rsub = lane >> 4;
    const int ch = lane & 15;
#pragma unroll
    for (int j = 0; j < 8; ++j) {
      int row = w * 32 + j * 4 + rsub;
      int sc_ = ch ^ (row & 7);
      const __hip_bfloat16* pC = xc + (size_t)(t0 + row) * CONVD + DI + DSTATE + sc_ * 8;
      __builtin_amdgcn_global_load_lds((const AS1 void*)pC,
                                       (AS3 void*)(sC + (w * 32 + j * 4) * 128), 16, 0, 0);
    }
#pragma unroll
    for (int j = 0; j < 4; ++j) {
      int row = w * 16 + j * 4 + rsub;
      int sc_ = ch ^ (row & 7);
      const __hip_bfloat16* pH = sbuf + (size_t)bid * 8192 + row * 128 + sc_ * 8;
      __builtin_amdgcn_global_load_lds((const AS1 void*)pH,
                                       (AS3 void*)(sH + (w * 16 + j * 4) * 128), 16, 0, 0);
    }
  }
  if (tid < 128) scd[tid] = cumdecb[(size_t)bid * 128 + tid];
  __syncthreads();

  const int fr = lane & 15;
  const int fk = (lane >> 4) * 8;
  const int rb = (lane >> 4) * 4;
  int tR0 = w * 32;
  f32x4 ac[2][4];
#pragma unroll
  for (int m = 0; m < 2; ++m)
#pragma unroll
    for (int n = 0; n < 4; ++n) ac[m][n] = (f32x4){0.f, 0.f, 0.f, 0.f};
  for (int kk = 0; kk < 128; kk += 32) {
    bf16x8 af[2], bfv[4];
#pragma unroll
    for (int m = 0; m < 2; ++m) af[m] = ldsfrag(sC, tR0 + m * 16 + fr, kk + fk);
#pragma unroll
    for (int n = 0; n < 4; ++n) bfv[n] = ldsfrag(sH, n * 16 + fr, kk + fk);
#pragma unroll
    for (int m = 0; m < 2; ++m)
#pragma unroll
      for (int n = 0; n < 4; ++n)
        ac[m][n] = __builtin_amdgcn_mfma_f32_16x16x32_bf16(af[m], bfv[n], ac[m][n], 0, 0, 0);
  }
#pragma unroll
  for (int m = 0; m < 2; ++m)
#pragma unroll
    for (int n = 0; n < 4; ++n) {
      int trow = tR0 + m * 16 + rb;
      int pc = n * 16 + fr;
      float* yp = y + ((size_t)b * LSEQ + t0 + trow) * DI + h * HD + pc;
#pragma unroll
      for (int j = 0; j < 4; ++j)
        yp[(size_t)j * DI] += scd[trow + j] * ac[m][n][j];
    }
}

// ---------------- gating + RMS norm -> bf16 ----------------

__global__ __launch_bounds__(256)
void gate_rms_kernel(const float* __restrict__ y, const float* __restrict__ zx,
                     const float* __restrict__ nw, __hip_bfloat16* __restrict__ g) {
  int row = blockIdx.x;
  int t = threadIdx.x;
  const float* yr = y + (size_t)row * DI;
  const float* zr = zx + (size_t)row * DPROJ_PAD;
  float v[8];
  float ss = 0.f;
#pragma unroll
  for (int j = 0; j < 8; ++j) {
    int c = j * 256 + t;
    float z = zr[c];
    float vv = yr[c] * (z / (1.f + expf(-z)));
    v[j] = vv;
    ss += vv * vv;
  }
#pragma unroll
  for (int off = 32; off; off >>= 1) ss += __shfl_down(ss, off);
  __shared__ float red[4];
  if ((t & 63) == 0) red[t >> 6] = ss;
  __syncthreads();
  float tot = red[0] + red[1] + red[2] + red[3];
  float rstd = rsqrtf(tot * (1.f / DI) + EPSV);
#pragma unroll
  for (int j = 0; j < 8; ++j) {
    int c = j * 256 + t;
    g[(size_t)row * DI + c] = __float2bfloat16(v[j] * rstd * nw[c]);
  }
}

// ---------------- final RMS + residual ----------------

__global__ __launch_bounds__(256)
void final_rms_add(const float* __restrict__ o1, const float* __restrict__ x,
                   float* __restrict__ out) {
  int row = blockIdx.x;
  int t = threadIdx.x;
  const float* orow = o1 + (size_t)row * DMODEL;
  float v[4];
  float ss = 0.f;
#pragma unroll
  for (int j = 0; j < 4; ++j) {
    int c = j * 256 + t;
    float o = orow[c];
    v[j] = o;
    ss += o * o;
  }
#pragma unroll
  for (int off = 32; off; off >>= 1) ss += __shfl_down(ss, off);
  __shared__ float red[4];
  if ((t & 63) == 0) red[t >> 6] = ss;
  __syncthreads();
  float tot = red[0] + red[1] + red[2] + red[3];
  float rstd = rsqrtf(tot * (1.f / DMODEL) + EPSV);
#pragma unroll
  for (int j = 0; j < 4; ++j) {
    int c = j * 256 + t;
    out[(size_t)row * DMODEL + c] = v[j] * rstd + x[(size_t)row * DMODEL + c];
  }
}

// ---------------- launch ----------------

extern "C" void kernel_launch(void* const* d_in, const int* in_sizes, int n_in,
                              void* d_out, int out_size, void* d_ws, size_t ws_size,
                              hipStream_t stream) {
  const float* x       = (const float*)d_in[0];
  const float* W_in    = (const float*)d_in[1];
  const float* conv_w  = (const float*)d_in[2];
  const float* conv_b  = (const float*)d_in[3];
  const float* dt_bias = (const float*)d_in[4];
  const float* A_log   = (const float*)d_in[5];
  const float* Dp      = (const float*)d_in[6];
  const float* norm_w  = (const float*)d_in[7];
  const float* W_out   = (const float*)d_in[8];
  float* out = (float*)d_out;

  float* zx   = (float*)d_ws;                               // 4096 x 4480 f32
  float* xbcF = zx + (size_t)18350080;
  __hip_bfloat16* xbc = (__hip_bfloat16*)xbcF;              // 4096 x 2304 bf16
  float* ybuf = xbcF + (size_t)9437184;                     // 4096 x 2048 f32
  float* dtb  = ybuf + (size_t)8388608;                     // 131072
  float* cumdecb = dtb + (size_t)131072;                    // 131072 (1024 x 128)
  __hip_bfloat16* xbf   = (__hip_bfloat16*)(cumdecb + 131072); // 4096x1024
  __hip_bfloat16* wtin  = xbf + (size_t)4194304;               // 4480x1024
  __hip_bfloat16* wtout = wtin + (size_t)4587520;              // 1024x2048
  float* pbuf = (float*)(wtout + (size_t)2097152);             // 1024
  float* csb  = pbuf + 1024;                                   // 1024 x 128
  float* dtc  = csb + (size_t)131072;                          // 1024 x 128
  float* swb  = dtc + (size_t)131072;                          // 1024 x 128
  __hip_bfloat16* sbuf = xbf;  // overlay: xbf/wtin dead after GEMM1
  __hip_bfloat16* gbf = xbf;   // overlay: sbuf dead after ssd_mfma_corr
  float* o1 = xbcF;            // overlay: xbc dead after ssd_mfma_corr

  f32_to_bf16_kernel<<<4096, 256, 0, stream>>>(x, xbf, 1048576);
  transpose_f32_bf16<<<dim3(140, 32), dim3(32, 8), 0, stream>>>(W_in, wtin, 1024, 4384, 4480);
  transpose_f32_bf16<<<dim3(32, 64), dim3(32, 8), 0, stream>>>(W_out, wtout, 2048, 1024, 1024);

  gemm_bt2<<<1120, 256, 0, stream>>>(xbf, wtin, zx, 4096, 4480, 1024);

  dtdecay_kernel<<<512, 256, 0, stream>>>(zx, dt_bias, dtb);
  chunk_stats_kernel<<<256, 256, 0, stream>>>(dtb, A_log, csb, dtc, swb, cumdecb, pbuf);
  conv_silu_kernel<<<9216, 256, 0, stream>>>(zx, conv_w, conv_b, xbc);

  ssd_mfma_local<<<1024, 256, 0, stream>>>(xbc, csb, dtc, swb, A_log, Dp, ybuf, sbuf);
  ssd_prop_kernel<<<2048, 256, 0, stream>>>(sbuf, pbuf);
  ssd_mfma_corr<<<1024, 256, 0, stream>>>(xbc, sbuf, cumdecb, ybuf);

  gate_rms_kernel<<<4096, 256, 0, stream>>>(ybuf, zx, norm_w, gbf);

  gemm_bt2<<<256, 256, 0, stream>>>(gbf, wtout, o1, 4096, 1024, 2048);

  final_rms_add<<<4096, 256, 0, stream>>>(o1, x, out);
}

// Round 9
// 217.242 us; speedup vs baseline: 2.1021x; 1.0243x over previous
//
#include <hip/hip_runtime.h>
#include <hip/hip_bf16.h>

#define DMODEL 1024
#define DI     2048
#define DSTATE 128
#define NH     32
#define HD     64
#define CONVD  2304
#define LSEQ   2048
#define BATCH  2
#define DPROJ  4384
#define DPROJ_PAD 4480
#define EPSV   1e-5f
#define QCH    128
#define NCH    16

#define AS1 __attribute__((address_space(1)))
#define AS3 __attribute__((address_space(3)))

typedef __attribute__((ext_vector_type(8))) short bf16x8;
typedef __attribute__((ext_vector_type(4))) float f32x4;

union U4 { ushort4 u; __hip_bfloat16 h[4]; };

__device__ __forceinline__ float bf2f(unsigned short u) {
  union { unsigned int i; float f; } c; c.i = ((unsigned)u) << 16; return c.f;
}
__device__ __forceinline__ ushort4 pack4(float x0, float x1, float x2, float x3) {
  U4 p;
  p.h[0] = __float2bfloat16(x0); p.h[1] = __float2bfloat16(x1);
  p.h[2] = __float2bfloat16(x2); p.h[3] = __float2bfloat16(x3);
  return p.u;
}

// ---- swizzled LDS helpers: [rows][128] bf16 tiles (256B rows), byte ^= (row&7)<<4 ----
__device__ __forceinline__ bf16x8 ldsfrag(const __hip_bfloat16* base, int row, int ke) {
  int byte = row * 256 + ke * 2;
  byte ^= (row & 7) << 4;
  return *reinterpret_cast<const bf16x8*>(reinterpret_cast<const char*>(base) + byte);
}
__device__ __forceinline__ void ldswr4(__hip_bfloat16* base, int row, int col4, ushort4 v) {
  int byte = row * 256 + col4 * 2;
  byte ^= (row & 7) << 4;
  *reinterpret_cast<ushort4*>(reinterpret_cast<char*>(base) + byte) = v;
}
__device__ __forceinline__ void ldswr8(__hip_bfloat16* base, int row, int colElem,
                                       unsigned lo, unsigned hi) {
  int byte = row * 256 + colElem * 2;
  byte ^= (row & 7) << 4;
  uint2 v; v.x = lo; v.y = hi;
  *reinterpret_cast<uint2*>(reinterpret_cast<char*>(base) + byte) = v;
}
// ---- swizzled helpers for [rows][64] bf16 tiles (128B rows), same XOR ----
__device__ __forceinline__ bf16x8 frag64(const __hip_bfloat16* base, int row, int ke) {
  int byte = row * 128 + ke * 2;
  byte ^= (row & 7) << 4;
  return *reinterpret_cast<const bf16x8*>(reinterpret_cast<const char*>(base) + byte);
}

// ---- in-register 4x4 u16 transpose across a quad (lanes ql=0..3) ----
__device__ __forceinline__ void quadtr(unsigned a01, unsigned a23, int ql,
                                       unsigned& w01, unsigned& w23) {
  unsigned y01 = __shfl_xor((int)a01, 1), y23 = __shfl_xor((int)a23, 1);
  unsigned c01 = (ql & 1) ? ((y01 >> 16) | (a01 & 0xFFFF0000u))
                          : ((a01 & 0xFFFFu) | (y01 << 16));
  unsigned c23 = (ql & 1) ? ((y23 >> 16) | (a23 & 0xFFFF0000u))
                          : ((a23 & 0xFFFFu) | (y23 << 16));
  unsigned d01 = __shfl_xor((int)c01, 2), d23 = __shfl_xor((int)c23, 2);
  w01 = (ql & 2) ? d23 : c01;
  w23 = (ql & 2) ? c23 : d01;
}

// ---------------- conversion kernels ----------------

__global__ void f32_to_bf16_kernel(const float* __restrict__ in,
                                   __hip_bfloat16* __restrict__ out, int n4) {
  int i = blockIdx.x * 256 + threadIdx.x;
  if (i >= n4) return;
  float4 v = reinterpret_cast<const float4*>(in)[i];
  reinterpret_cast<ushort4*>(out)[i] = pack4(v.x, v.y, v.z, v.w);
}

__global__ void transpose_f32_bf16(const float* __restrict__ in,
                                   __hip_bfloat16* __restrict__ out,
                                   int R, int C, int Cpad) {
  __shared__ float tile[32][33];
  int n0 = blockIdx.x * 32, k0 = blockIdx.y * 32;
  int tx = threadIdx.x, ty = threadIdx.y;  // (32,8)
#pragma unroll
  for (int j = 0; j < 32; j += 8) {
    int k = k0 + ty + j, n = n0 + tx;
    tile[ty + j][tx] = (n < C) ? in[(size_t)k * C + n] : 0.f;
  }
  __syncthreads();
#pragma unroll
  for (int j = 0; j < 32; j += 8) {
    int n = n0 + ty + j, k = k0 + tx;
    if (n < Cpad) out[(size_t)n * R + k] = __float2bfloat16(tile[tx][ty + j]);
  }
}

// ---------------- GEMM: 128x128 tile, BK=64, dbuf 2-phase, T2 swizzle ----------------
// OUTMODE 0: f32 C.  OUTMODE 1: bf16 C + f32 side-write of dt cols [4352,4384) to dtraw.
// XCD owns 4 consecutive M-panels, m-fastest iteration (B-panels stay L2-hot).

template <int OUTMODE>
__global__ __launch_bounds__(256, 2)
void gemm_bt2(const __hip_bfloat16* __restrict__ A,
              const __hip_bfloat16* __restrict__ Bt,
              void* __restrict__ Cout, float* __restrict__ dtraw,
              int M, int N, int K) {
  __shared__ __hip_bfloat16 smA[2][128 * 64];
  __shared__ __hip_bfloat16 smB[2][128 * 64];
  const int xcd = blockIdx.x & 7;
  const int i = blockIdx.x >> 3;
  const int bm = ((xcd << 2) + (i & 3)) * 128;
  const int bn = (i >> 2) * 128;
  const int t = threadIdx.x;
  const int w = t >> 6, lane = t & 63;
  const int wr = (w >> 1) * 64, wc = (w & 1) * 64;
  const int fr = lane & 15, fk = (lane >> 4) * 8;
  const int srow = lane >> 3;
  const int scol = ((lane & 7) ^ srow) * 8;

  f32x4 acc[4][4];
#pragma unroll
  for (int m = 0; m < 4; ++m)
#pragma unroll
    for (int n = 0; n < 4; ++n) acc[m][n] = (f32x4){0.f, 0.f, 0.f, 0.f};

  const __hip_bfloat16* aSrc = A + (size_t)(bm + srow) * K + scol;
  const __hip_bfloat16* bSrc = Bt + (size_t)(bn + srow) * K + scol;

  auto STAGE = [&](int buf, int k0) {
#pragma unroll
    for (int i2 = 0; i2 < 4; ++i2) {
      int ro = w * 32 + i2 * 8;
      __builtin_amdgcn_global_load_lds((const AS1 void*)(aSrc + (size_t)ro * K + k0),
                                       (AS3 void*)(&smA[buf][ro * 64]), 16, 0, 0);
      __builtin_amdgcn_global_load_lds((const AS1 void*)(bSrc + (size_t)ro * K + k0),
                                       (AS3 void*)(&smB[buf][ro * 64]), 16, 0, 0);
    }
  };

  STAGE(0, 0);
  __syncthreads();
  const int nt = K >> 6;
  int cur = 0;
  for (int kt = 0; kt < nt; ++kt) {
    if (kt + 1 < nt) STAGE(cur ^ 1, (kt + 1) << 6);
#pragma unroll
    for (int kk = 0; kk < 64; kk += 32) {
      bf16x8 af[4], bfv[4];
#pragma unroll
      for (int m = 0; m < 4; ++m) af[m] = frag64(&smA[cur][0], wr + m * 16 + fr, kk + fk);
#pragma unroll
      for (int n = 0; n < 4; ++n) bfv[n] = frag64(&smB[cur][0], wc + n * 16 + fr, kk + fk);
#pragma unroll
      for (int m = 0; m < 4; ++m)
#pragma unroll
        for (int n = 0; n < 4; ++n)
          acc[m][n] = __builtin_amdgcn_mfma_f32_16x16x32_bf16(af[m], bfv[n], acc[m][n], 0, 0, 0);
    }
    __syncthreads();
    cur ^= 1;
  }

  const int r4 = (lane >> 4) * 4;
  const int cn = lane & 15;
#pragma unroll
  for (int m = 0; m < 4; ++m)
#pragma unroll
    for (int n = 0; n < 4; ++n) {
      int row = bm + wr + m * 16 + r4;
      int col = bn + wc + n * 16 + cn;
      if constexpr (OUTMODE == 0) {
        float* cp = (float*)Cout + (size_t)row * N + col;
#pragma unroll
        for (int j = 0; j < 4; ++j) cp[(size_t)j * N] = acc[m][n][j];
      } else {
        __hip_bfloat16* cp = (__hip_bfloat16*)Cout + (size_t)row * N + col;
#pragma unroll
        for (int j = 0; j < 4; ++j) {
          float v = acc[m][n][j];
          cp[(size_t)j * N] = __float2bfloat16(v);
          if (col >= DI + CONVD && col < DPROJ)
            dtraw[(size_t)(row + j) * NH + (col - (DI + CONVD))] = v;
        }
      }
    }
}

// ---------------- per-chunk softplus + cumsum / decay stats (one wave per (b,h,c)) ----

__global__ __launch_bounds__(256)
void chunk_stats_kernel(const float* __restrict__ dtraw, const float* __restrict__ dt_bias,
                        const float* __restrict__ A_log,
                        float* __restrict__ csb, float* __restrict__ dtc,
                        float* __restrict__ swb, float* __restrict__ cumdecb,
                        float* __restrict__ pbuf) {
  int w = threadIdx.x >> 6, lane = threadIdx.x & 63;
  int bid = blockIdx.x * 4 + w;           // 0..1023
  int c = bid & (NCH - 1);
  int h = (bid >> 4) & 31;
  int b = bid >> 9;
  int t0 = c * QCH;
  float a = expf(A_log[h]);
  float bias = dt_bias[h];
  const float* dtp = dtraw + ((size_t)b * LSEQ + t0) * NH + h;
  float r0 = dtp[lane * NH] + bias;
  float r1 = dtp[(64 + lane) * NH] + bias;
  float v0 = (r0 > 20.f) ? r0 : log1pf(expf(r0));
  float v1 = (r1 > 20.f) ? r1 : log1pf(expf(r1));
  float s0 = v0;
#pragma unroll
  for (int off = 1; off < 64; off <<= 1) {
    float tv = __shfl_up(s0, off);
    if (lane >= off) s0 += tv;
  }
  float T0 = __shfl(s0, 63);
  float s1 = v1;
#pragma unroll
  for (int off = 1; off < 64; off <<= 1) {
    float tv = __shfl_up(s1, off);
    if (lane >= off) s1 += tv;
  }
  float cs1 = s1 + T0;
  float Tt = __shfl(s1, 63) + T0;
  size_t base = (size_t)bid * 128;
  csb[base + lane] = s0;        csb[base + 64 + lane] = cs1;
  dtc[base + lane] = v0;        dtc[base + 64 + lane] = v1;
  swb[base + lane] = v0 * expf(-a * (Tt - s0));
  swb[base + 64 + lane] = v1 * expf(-a * (Tt - cs1));
  cumdecb[base + lane] = expf(-a * s0);
  cumdecb[base + 64 + lane] = expf(-a * cs1);
  if (lane == 0) pbuf[bid] = expf(-a * Tt);
}

// ---------------- causal depthwise conv + silu: bf16 in -> bf16 out ----------------

__global__ void conv_silu_kernel(const __hip_bfloat16* __restrict__ zxb,
                                 const float* __restrict__ cw,
                                 const float* __restrict__ cb,
                                 __hip_bfloat16* __restrict__ xbc) {
  int idx = blockIdx.x * 256 + threadIdx.x;
  if (idx >= BATCH * LSEQ * (CONVD / 4)) return;
  int c4 = idx % (CONVD / 4);
  int bl = idx / (CONVD / 4);
  int l = bl % LSEQ;
  int b = bl / LSEQ;
  int c0 = c4 * 4;
  const __hip_bfloat16* src = zxb + (size_t)b * LSEQ * DPROJ_PAD + DI + c0;
  float4 w0 = *reinterpret_cast<const float4*>(cw + (c0 + 0) * 4);
  float4 w1 = *reinterpret_cast<const float4*>(cw + (c0 + 1) * 4);
  float4 w2 = *reinterpret_cast<const float4*>(cw + (c0 + 2) * 4);
  float4 w3 = *reinterpret_cast<const float4*>(cw + (c0 + 3) * 4);
  float4 acc = *reinterpret_cast<const float4*>(cb + c0);
  if (l >= 3) { ushort4 v = *reinterpret_cast<const ushort4*>(src + (size_t)(l - 3) * DPROJ_PAD);
    acc.x += w0.x * bf2f(v.x); acc.y += w1.x * bf2f(v.y); acc.z += w2.x * bf2f(v.z); acc.w += w3.x * bf2f(v.w); }
  if (l >= 2) { ushort4 v = *reinterpret_cast<const ushort4*>(src + (size_t)(l - 2) * DPROJ_PAD);
    acc.x += w0.y * bf2f(v.x); acc.y += w1.y * bf2f(v.y); acc.z += w2.y * bf2f(v.z); acc.w += w3.y * bf2f(v.w); }
  if (l >= 1) { ushort4 v = *reinterpret_cast<const ushort4*>(src + (size_t)(l - 1) * DPROJ_PAD);
    acc.x += w0.z * bf2f(v.x); acc.y += w1.z * bf2f(v.y); acc.z += w2.z * bf2f(v.z); acc.w += w3.z * bf2f(v.w); }
  { ushort4 v = *reinterpret_cast<const ushort4*>(src + (size_t)l * DPROJ_PAD);
    acc.x += w0.w * bf2f(v.x); acc.y += w1.w * bf2f(v.y); acc.z += w2.w * bf2f(v.z); acc.w += w3.w * bf2f(v.w); }
  acc.x = acc.x / (1.f + expf(-acc.x));
  acc.y = acc.y / (1.f + expf(-acc.y));
  acc.z = acc.z / (1.f + expf(-acc.z));
  acc.w = acc.w / (1.f + expf(-acc.w));
  *reinterpret_cast<ushort4*>(xbc + (size_t)bl * CONVD + c0) = pack4(acc.x, acc.y, acc.z, acc.w);
}

// ---------------- SSD pass 1: per-chunk MFMA ----------------
// LDS 80KB -> 2 blocks/CU. T_B: B -> P; T_C: C -> Bw^T; T_X: X^T.

__global__ __launch_bounds__(256, 2)
void ssd_mfma_local(const __hip_bfloat16* __restrict__ bxc,
                    const float* __restrict__ csb, const float* __restrict__ dtc,
                    const float* __restrict__ swb,
                    const float* __restrict__ A_log, const float* __restrict__ Dparm,
                    float* __restrict__ y, __hip_bfloat16* __restrict__ sbuf) {
  __shared__ __hip_bfloat16 T_B[128 * 128];
  __shared__ __hip_bfloat16 T_C[128 * 128];
  __shared__ __hip_bfloat16 T_X[64 * 128];

  const int bid = blockIdx.x;
  const int c = bid & (NCH - 1);
  const int h = (bid >> 4) & 31;
  const int b = bid >> 9;
  const int tid = threadIdx.x;
  const int w = tid >> 6, lane = tid & 63;
  const int q = lane >> 2, ql = lane & 3;
  const int t0 = c * QCH;
  const __hip_bfloat16* xc = bxc + (size_t)b * LSEQ * CONVD;
  const float a = expf(A_log[h]);
  const float Dh = Dparm[h];

  // ---- stage B, C via global_load_lds (pre-swizzled source chunks) ----
  {
    const int rsub = lane >> 4;
    const int ch = lane & 15;
#pragma unroll
    for (int j = 0; j < 8; ++j) {
      int row = w * 32 + j * 4 + rsub;
      int sc_ = ch ^ (row & 7);
      const __hip_bfloat16* pB = xc + (size_t)(t0 + row) * CONVD + DI + sc_ * 8;
      __builtin_amdgcn_global_load_lds((const AS1 void*)pB,
                                       (AS3 void*)(T_B + (w * 32 + j * 4) * 128), 16, 0, 0);
      __builtin_amdgcn_global_load_lds((const AS1 void*)(pB + DSTATE),
                                       (AS3 void*)(T_C + (w * 32 + j * 4) * 128), 16, 0, 0);
    }
  }
  // ---- stage X^T via quad transpose (8B swizzled writes) ----
#pragma unroll
  for (int r = 0; r < 8; ++r) {
    int gidx = w * 128 + q * 8 + r;     // 0..511
    int tb = (gidx & 31) * 4;
    int pb = (gidx >> 5) * 4;
    int t = tb + ql;
    ushort4 xv = *reinterpret_cast<const ushort4*>(xc + (size_t)(t0 + t) * CONVD + h * HD + pb);
    unsigned a01 = (unsigned)xv.x | ((unsigned)xv.y << 16);
    unsigned a23 = (unsigned)xv.z | ((unsigned)xv.w << 16);
    unsigned w01, w23;
    quadtr(a01, a23, ql, w01, w23);
    ldswr8(T_X, pb + ql, tb, w01, w23);
  }
  __syncthreads();

  const int fr = lane & 15;
  const int fk = (lane >> 4) * 8;
  const int rb = (lane >> 4) * 4;

  // ---- phase 2: G^T[s][t] = sum_n B[s][n] C[t][n]; wave quadrant 64x64 ----
  const int sR0 = (w >> 1) * 64, tC0 = (w & 1) * 64;
  f32x4 g[4][4];
#pragma unroll
  for (int m = 0; m < 4; ++m)
#pragma unroll
    for (int n = 0; n < 4; ++n) g[m][n] = (f32x4){0.f, 0.f, 0.f, 0.f};
  for (int kk = 0; kk < 128; kk += 32) {
    bf16x8 af[4], bfv[4];
#pragma unroll
    for (int m = 0; m < 4; ++m) af[m] = ldsfrag(T_B, sR0 + m * 16 + fr, kk + fk);
#pragma unroll
    for (int n = 0; n < 4; ++n) bfv[n] = ldsfrag(T_C, tC0 + n * 16 + fr, kk + fk);
#pragma unroll
    for (int m = 0; m < 4; ++m)
#pragma unroll
      for (int n = 0; n < 4; ++n)
        g[m][n] = __builtin_amdgcn_mfma_f32_16x16x32_bf16(af[m], bfv[n], g[m][n], 0, 0, 0);
  }
  __syncthreads();  // all waves done reading T_B/T_C

  // ---- mask L (+D diag) -> write P[t][s] into T_B; build Bw^T into T_C ----
  {
    const float* csp = csb + (size_t)bid * 128;
    const float* dtp = dtc + (size_t)bid * 128;
#pragma unroll
    for (int m = 0; m < 4; ++m) {
      int sb0 = sR0 + m * 16 + rb;
      float cs_s[4], dt_s[4];
#pragma unroll
      for (int j = 0; j < 4; ++j) { cs_s[j] = csp[sb0 + j]; dt_s[j] = dtp[sb0 + j]; }
#pragma unroll
      for (int n = 0; n < 4; ++n) {
        int tt = tC0 + n * 16 + fr;
        float cst = csp[tt];
        float vv[4];
#pragma unroll
        for (int j = 0; j < 4; ++j) {
          int s = sb0 + j;
          float e = __expf(-a * (cst - cs_s[j])) * dt_s[j];
          float pv = (s <= tt) ? g[m][n][j] * e : 0.f;
          vv[j] = pv + ((s == tt) ? Dh : 0.f);
        }
        ldswr4(T_B, tt, sb0, pack4(vv[0], vv[1], vv[2], vv[3]));
      }
    }
    // Bw^T build: scale rows by w_t, quad-transpose, 8B writes
    const float* swp = swb + (size_t)bid * 128;
#pragma unroll
    for (int r = 0; r < 16; ++r) {
      int gidx = w * 256 + q * 16 + r;   // 0..1023
      int tb = (gidx & 31) * 4;
      int nb = (gidx >> 5) * 4;
      int t = tb + ql;
      ushort4 bv = *reinterpret_cast<const ushort4*>(xc + (size_t)(t0 + t) * CONVD + DI + nb);
      float wt = swp[t];
      ushort4 sv = pack4(bf2f(bv.x) * wt, bf2f(bv.y) * wt, bf2f(bv.z) * wt, bf2f(bv.w) * wt);
      unsigned a01 = (unsigned)sv.x | ((unsigned)sv.y << 16);
      unsigned a23 = (unsigned)sv.z | ((unsigned)sv.w << 16);
      unsigned w01, w23;
      quadtr(a01, a23, ql, w01, w23);
      ldswr8(T_C, nb + ql, tb, w01, w23);
    }
  }
  __syncthreads();

  // ---- phase 3: Y[t][p] = sum_s P[t][s] X[s][p] ----
  {
    int tR0 = w * 32;
    f32x4 yac[2][4];
#pragma unroll
    for (int m = 0; m < 2; ++m)
#pragma unroll
      for (int n = 0; n < 4; ++n) yac[m][n] = (f32x4){0.f, 0.f, 0.f, 0.f};
    for (int kk = 0; kk < 128; kk += 32) {
      bf16x8 af[2], bfv[4];
#pragma unroll
      for (int m = 0; m < 2; ++m) af[m] = ldsfrag(T_B, tR0 + m * 16 + fr, kk + fk);
#pragma unroll
      for (int n = 0; n < 4; ++n) bfv[n] = ldsfrag(T_X, n * 16 + fr, kk + fk);
#pragma unroll
      for (int m = 0; m < 2; ++m)
#pragma unroll
        for (int n = 0; n < 4; ++n)
          yac[m][n] = __builtin_amdgcn_mfma_f32_16x16x32_bf16(af[m], bfv[n], yac[m][n], 0, 0, 0);
    }
#pragma unroll
    for (int m = 0; m < 2; ++m)
#pragma unroll
      for (int n = 0; n < 4; ++n) {
        int trow = tR0 + m * 16 + rb;
        int pc = n * 16 + fr;
        float* yp = y + ((size_t)b * LSEQ + t0 + trow) * DI + h * HD + pc;
#pragma unroll
        for (int j = 0; j < 4; ++j)
          yp[(size_t)j * DI] = yac[m][n][j];
      }
  }

  // ---- phase 4: S^T[p][n] = sum_t XT[p][t] BwT[n][t] -> sbuf[bid][p][n] ----
  {
    int pR0 = (w >> 1) * 32, nC0 = (w & 1) * 64;
    f32x4 sac[2][4];
#pragma unroll
    for (int m = 0; m < 2; ++m)
#pragma unroll
      for (int n = 0; n < 4; ++n) sac[m][n] = (f32x4){0.f, 0.f, 0.f, 0.f};
    for (int kk = 0; kk < 128; kk += 32) {
      bf16x8 af[2], bfv[4];
#pragma unroll
      for (int m = 0; m < 2; ++m) af[m] = ldsfrag(T_X, pR0 + m * 16 + fr, kk + fk);
#pragma unroll
      for (int n = 0; n < 4; ++n) bfv[n] = ldsfrag(T_C, nC0 + n * 16 + fr, kk + fk);
#pragma unroll
      for (int m = 0; m < 2; ++m)
#pragma unroll
        for (int n = 0; n < 4; ++n)
          sac[m][n] = __builtin_amdgcn_mfma_f32_16x16x32_bf16(af[m], bfv[n], sac[m][n], 0, 0, 0);
    }
    __hip_bfloat16* sg = sbuf + (size_t)bid * 8192;
#pragma unroll
    for (int m = 0; m < 2; ++m)
#pragma unroll
      for (int n = 0; n < 4; ++n) {
        int p = pR0 + m * 16 + rb;
        int nn = nC0 + n * 16 + fr;
#pragma unroll
        for (int j = 0; j < 4; ++j)
          sg[(size_t)(p + j) * 128 + nn] = __float2bfloat16(sac[m][n][j]);
      }
  }
}

// ---------------- SSD pass 2: propagate chunk states ----------------

__global__ void ssd_prop_kernel(__hip_bfloat16* __restrict__ sbuf,
                                const float* __restrict__ pbuf) {
  int idx = blockIdx.x * 256 + threadIdx.x;   // 64 * 8192
  int bh = idx >> 13;
  int e = idx & 8191;
  __hip_bfloat16* base = sbuf + (size_t)bh * NCH * 8192 + e;
  const float* pb = pbuf + bh * NCH;
  float hs = 0.f;
  for (int cc = 0; cc < NCH; ++cc) {
    float sc = __bfloat162float(base[(size_t)cc * 8192]);
    base[(size_t)cc * 8192] = __float2bfloat16(hs);
    hs = fmaf(hs, pb[cc], sc);
  }
}

// ---------------- SSD pass 3: Y += diag(cumdec) * C @ h_start (MFMA) ----------------

__global__ __launch_bounds__(256)
void ssd_mfma_corr(const __hip_bfloat16* __restrict__ bxc, const __hip_bfloat16* __restrict__ sbuf,
                   const float* __restrict__ cumdecb, float* __restrict__ y) {
  __shared__ __hip_bfloat16 sC[128 * 128];
  __shared__ __hip_bfloat16 sH[64 * 128];
  __shared__ float scd[128];
  const int bid = blockIdx.x;
  const int c = bid & (NCH - 1);
  if (c == 0) return;  // block-uniform exit
  const int h = (bid >> 4) & 31;
  const int b = bid >> 9;
  const int tid = threadIdx.x;
  const int w = tid >> 6, lane = tid & 63;
  const int t0 = c * QCH;
  const __hip_bfloat16* xc = bxc + (size_t)b * LSEQ * CONVD;

  {
    const int rsub = lane >> 4;
    const int ch = lane & 15;
#pragma unroll
    for (int j = 0; j < 8; ++j) {
      int row = w * 32 + j * 4 + rsub;
      int sc_ = ch ^ (row & 7);
      const __hip_bfloat16* pC = xc + (size_t)(t0 + row) * CONVD + DI + DSTATE + sc_ * 8;
      __builtin_amdgcn_global_load_lds((const AS1 void*)pC,
                                       (AS3 void*)(sC + (w * 32 + j * 4) * 128), 16, 0, 0);
    }
#pragma unroll
    for (int j = 0; j < 4; ++j) {
      int row = w * 16 + j * 4 + rsub;
      int sc_ = ch ^ (row & 7);
      const __hip_bfloat16* pH = sbuf + (size_t)bid * 8192 + row * 128 + sc_ * 8;
      __builtin_amdgcn_global_load_lds((const AS1 void*)pH,
                                       (AS3 void*)(sH + (w * 16 + j * 4) * 128), 16, 0, 0);
    }
  }
  if (tid < 128) scd[tid] = cumdecb[(size_t)bid * 128 + tid];
  __syncthreads();

  const int fr = lane & 15;
  const int fk = (lane >> 4) * 8;
  const int rb = (lane >> 4) * 4;
  int tR0 = w * 32;
  f32x4 ac[2][4];
#pragma unroll
  for (int m = 0; m < 2; ++m)
#pragma unroll
    for (int n = 0; n < 4; ++n) ac[m][n] = (f32x4){0.f, 0.f, 0.f, 0.f};
  for (int kk = 0; kk < 128; kk += 32) {
    bf16x8 af[2], bfv[4];
#pragma unroll
    for (int m = 0; m < 2; ++m) af[m] = ldsfrag(sC, tR0 + m * 16 + fr, kk + fk);
#pragma unroll
    for (int n = 0; n < 4; ++n) bfv[n] = ldsfrag(sH, n * 16 + fr, kk + fk);
#pragma unroll
    for (int m = 0; m < 2; ++m)
#pragma unroll
      for (int n = 0; n < 4; ++n)
        ac[m][n] = __builtin_amdgcn_mfma_f32_16x16x32_bf16(af[m], bfv[n], ac[m][n], 0, 0, 0);
  }
#pragma unroll
  for (int m = 0; m < 2; ++m)
#pragma unroll
    for (int n = 0; n < 4; ++n) {
      int trow = tR0 + m * 16 + rb;
      int pc = n * 16 + fr;
      float* yp = y + ((size_t)b * LSEQ + t0 + trow) * DI + h * HD + pc;
#pragma unroll
      for (int j = 0; j < 4; ++j)
        yp[(size_t)j * DI] += scd[trow + j] * ac[m][n][j];
    }
}

// ---------------- gating + RMS norm -> bf16 (vectorized: 8 cols/thread) ----------------

__global__ __launch_bounds__(256)
void gate_rms_kernel(const float* __restrict__ y, const __hip_bfloat16* __restrict__ zxb,
                     const float* __restrict__ nw, __hip_bfloat16* __restrict__ g) {
  int row = blockIdx.x;
  int t = threadIdx.x;
  int c0 = t * 8;
  const float* yr = y + (size_t)row * DI + c0;
  const __hip_bfloat16* zr = zxb + (size_t)row * DPROJ_PAD + c0;
  float4 ya = *reinterpret_cast<const float4*>(yr);
  float4 yb = *reinterpret_cast<const float4*>(yr + 4);
  ushort4 z0 = *reinterpret_cast<const ushort4*>(zr);
  ushort4 z1 = *reinterpret_cast<const ushort4*>(zr + 4);
  float zf[8] = {bf2f(z0.x), bf2f(z0.y), bf2f(z0.z), bf2f(z0.w),
                 bf2f(z1.x), bf2f(z1.y), bf2f(z1.z), bf2f(z1.w)};
  float yf[8] = {ya.x, ya.y, ya.z, ya.w, yb.x, yb.y, yb.z, yb.w};
  float v[8];
  float ss = 0.f;
#pragma unroll
  for (int j = 0; j < 8; ++j) {
    float z = zf[j];
    float vv = yf[j] * (z / (1.f + expf(-z)));
    v[j] = vv;
    ss += vv * vv;
  }
#pragma unroll
  for (int off = 32; off; off >>= 1) ss += __shfl_down(ss, off);
  __shared__ float red[4];
  if ((t & 63) == 0) red[t >> 6] = ss;
  __syncthreads();
  float tot = red[0] + red[1] + red[2] + red[3];
  float rstd = rsqrtf(tot * (1.f / DI) + EPSV);
  float4 na = *reinterpret_cast<const float4*>(nw + c0);
  float4 nb = *reinterpret_cast<const float4*>(nw + c0 + 4);
  ushort4 o0 = pack4(v[0] * rstd * na.x, v[1] * rstd * na.y,
                     v[2] * rstd * na.z, v[3] * rstd * na.w);
  ushort4 o1v = pack4(v[4] * rstd * nb.x, v[5] * rstd * nb.y,
                      v[6] * rstd * nb.z, v[7] * rstd * nb.w);
  ushort4* gp = reinterpret_cast<ushort4*>(g + (size_t)row * DI + c0);
  gp[0] = o0;
  gp[1] = o1v;
}

// ---------------- final RMS + residual (vectorized: 4 cols/thread) ----------------

__global__ __launch_bounds__(256)
void final_rms_add(const float* __restrict__ o1, const float* __restrict__ x,
                   float* __restrict__ out) {
  int row = blockIdx.x;
  int t = threadIdx.x;
  int c0 = t * 4;
  float4 o = *reinterpret_cast<const float4*>(o1 + (size_t)row * DMODEL + c0);
  float ss = o.x * o.x + o.y * o.y + o.z * o.z + o.w * o.w;
#pragma unroll
  for (int off = 32; off; off >>= 1) ss += __shfl_down(ss, off);
  __shared__ float red[4];
  if ((t & 63) == 0) red[t >> 6] = ss;
  __syncthreads();
  float tot = red[0] + red[1] + red[2] + red[3];
  float rstd = rsqrtf(tot * (1.f / DMODEL) + EPSV);
  float4 xv = *reinterpret_cast<const float4*>(x + (size_t)row * DMODEL + c0);
  float4 r;
  r.x = o.x * rstd + xv.x;
  r.y = o.y * rstd + xv.y;
  r.z = o.z * rstd + xv.z;
  r.w = o.w * rstd + xv.w;
  *reinterpret_cast<float4*>(out + (size_t)row * DMODEL + c0) = r;
}

// ---------------- launch ----------------

extern "C" void kernel_launch(void* const* d_in, const int* in_sizes, int n_in,
                              void* d_out, int out_size, void* d_ws, size_t ws_size,
                              hipStream_t stream) {
  const float* x       = (const float*)d_in[0];
  const float* W_in    = (const float*)d_in[1];
  const float* conv_w  = (const float*)d_in[2];
  const float* conv_b  = (const float*)d_in[3];
  const float* dt_bias = (const float*)d_in[4];
  const float* A_log   = (const float*)d_in[5];
  const float* Dp      = (const float*)d_in[6];
  const float* norm_w  = (const float*)d_in[7];
  const float* W_out   = (const float*)d_in[8];
  float* out = (float*)d_out;

  float* zxF  = (float*)d_ws;                               // slot: 4096 x 4480 (zx bf16 lives here)
  __hip_bfloat16* zxb = (__hip_bfloat16*)zxF;               // 4096 x 4480 bf16
  float* xbcF = zxF + (size_t)18350080;
  __hip_bfloat16* xbc = (__hip_bfloat16*)xbcF;              // 4096 x 2304 bf16
  float* ybuf = xbcF + (size_t)9437184;                     // 4096 x 2048 f32
  float* dtraw = ybuf + (size_t)8388608;                    // 131072 (4096 x 32 f32)
  float* cumdecb = dtraw + (size_t)131072;                  // 131072 (1024 x 128)
  __hip_bfloat16* xbf   = (__hip_bfloat16*)(cumdecb + 131072); // 4096x1024
  __hip_bfloat16* wtin  = xbf + (size_t)4194304;               // 4480x1024
  __hip_bfloat16* wtout = wtin + (size_t)4587520;              // 1024x2048
  float* pbuf = (float*)(wtout + (size_t)2097152);             // 1024
  float* csb  = pbuf + 1024;                                   // 1024 x 128
  float* dtc  = csb + (size_t)131072;                          // 1024 x 128
  float* swb  = dtc + (size_t)131072;                          // 1024 x 128
  __hip_bfloat16* sbuf = xbf;  // overlay: xbf/wtin dead after GEMM1
  __hip_bfloat16* gbf = xbf;   // overlay: sbuf dead after ssd_mfma_corr
  float* o1 = xbcF;            // overlay: xbc dead after ssd_mfma_corr

  f32_to_bf16_kernel<<<4096, 256, 0, stream>>>(x, xbf, 1048576);
  transpose_f32_bf16<<<dim3(140, 32), dim3(32, 8), 0, stream>>>(W_in, wtin, 1024, 4384, 4480);
  transpose_f32_bf16<<<dim3(32, 64), dim3(32, 8), 0, stream>>>(W_out, wtout, 2048, 1024, 1024);

  gemm_bt2<1><<<1120, 256, 0, stream>>>(xbf, wtin, (void*)zxb, dtraw, 4096, 4480, 1024);

  chunk_stats_kernel<<<256, 256, 0, stream>>>(dtraw, dt_bias, A_log, csb, dtc, swb, cumdecb, pbuf);
  conv_silu_kernel<<<9216, 256, 0, stream>>>(zxb, conv_w, conv_b, xbc);

  ssd_mfma_local<<<1024, 256, 0, stream>>>(xbc, csb, dtc, swb, A_log, Dp, ybuf, sbuf);
  ssd_prop_kernel<<<2048, 256, 0, stream>>>(sbuf, pbuf);
  ssd_mfma_corr<<<1024, 256, 0, stream>>>(xbc, sbuf, cumdecb, ybuf);

  gate_rms_kernel<<<4096, 256, 0, stream>>>(ybuf, zxb, norm_w, gbf);

  gemm_bt2<0><<<256, 256, 0, stream>>>(gbf, wtout, (void*)o1, nullptr, 4096, 1024, 2048);

  final_rms_add<<<4096, 256, 0, stream>>>(o1, x, out);
}